// Round 3
// baseline (623.114 us; speedup 1.0000x reference)
//
#include <hip/hip_runtime.h>
#include <hip/hip_cooperative_groups.h>
#include <cstdint>

namespace cg = cooperative_groups;

#define NENT 100000
#define EPS 1e-5f

// ---- ws layout (float offsets) ----
constexpr long REL_A    = 0;        // 2500
constexpr long REL_B    = 2500;     // 2500
constexpr long EPART    = 5000;     // 16 (8 blocks x {sum, sumsq})
constexpr long P2S_OFF  = 5056;     // 400 (4 chunks x 100 ch)
constexpr long P2Q_OFF  = 5456;     // 400
constexpr long PART_OFF = 5888;     // 4*1024*100 = 409600
constexpr long XBUF_OFF = 415488;   // 1024*3600  = 3686400
constexpr long XHAT_OFF = 4101888;  // 1024*128 bf16 = 32768 floats
// P1 partials overlap XBUF (dead before conv writes it):
constexpr long P1S_OFF  = XBUF_OFF;            // 256*2500 = 640000
constexpr long P1Q_OFF  = XBUF_OFF + 640000;   // 640000

typedef __attribute__((ext_vector_type(8))) __bf16 bf16x8;
typedef __attribute__((ext_vector_type(4))) float  f32x4;

__device__ __forceinline__ unsigned short f2bf(float f) {
    unsigned int u = __float_as_uint(f);
    unsigned int r = (u + 0x7FFFu + ((u >> 16) & 1u)) >> 16;
    return (unsigned short)r;
}

// ============ Fused pre-GEMM cooperative kernel: 512 blocks x 256 ============
__global__ void __launch_bounds__(256, 2)
k_pre(const int* __restrict__ rel, const float* __restrict__ emb_rel,
      const float* __restrict__ grel, const float* __restrict__ brel,
      const int* __restrict__ e1, const float* __restrict__ emb_e,
      const float* __restrict__ g0, const float* __restrict__ b0,
      const float* __restrict__ g1, const float* __restrict__ b1,
      const float* __restrict__ fc_w, const float* __restrict__ fc_b,
      const float* __restrict__ g2, const float* __restrict__ b2,
      float* __restrict__ ws) {
    __shared__ float smem[5200];   // 20.8 KB, unioned across phases
    cg::grid_group grid = cg::this_grid();
    int tid = threadIdx.x;
    int blk = blockIdx.x;
    float* xbuf = ws + XBUF_OFF;
    float* part = ws + PART_OFF;
    unsigned short* xhat = (unsigned short*)(ws + XHAT_OFF);

    // ---------- P0 level1: blocks 0..255 stream 4 rel rows each into LDS accumulators ----------
    if (blk < 256) {
        float* sums = smem;         // 2500
        float* sqs  = smem + 2560;  // 2500
        for (int i = tid; i < 2500; i += 256) { sums[i] = 0.f; sqs[i] = 0.f; }
        __syncthreads();
#pragma unroll
        for (int rr = 0; rr < 4; rr++) {
            long rb = (long)rel[blk * 4 + rr] * 2500;
            for (int i = tid; i < 2500; i += 256) {
                float v = emb_rel[rb + i];
                sums[i] += v; sqs[i] += v * v;
            }
        }
        for (int i = tid; i < 2500; i += 256) {
            ws[P1S_OFF + (long)blk * 2500 + i] = sums[i];
            ws[P1Q_OFF + (long)blk * 2500 + i] = sqs[i];
        }
    } else if (blk < 264) {
        // e-embedding scalar-BN partials: 8 blocks x 128 rows
        int* eidx = (int*)(smem + 512);
        float* ps = smem; float* pq = smem + 256;
        int bi = blk - 256;
        if (tid < 128) eidx[tid] = e1[bi * 128 + tid];
        __syncthreads();
        float s = 0.f, q = 0.f;
        for (int i = tid; i < 12800; i += 256) {
            int b = i / 100, d = i - b * 100;
            float v = emb_e[(long)eidx[b] * 100 + d];
            s += v; q += v * v;
        }
        ps[tid] = s; pq[tid] = q;
        __syncthreads();
        for (int off = 128; off > 0; off >>= 1) {
            if (tid < off) { ps[tid] += ps[tid + off]; pq[tid] += pq[tid + off]; }
            __syncthreads();
        }
        if (tid == 0) { ws[EPART + bi * 2] = ps[0]; ws[EPART + bi * 2 + 1] = pq[0]; }
    }
    grid.sync();   // S1

    // ---------- P0 level2: 40 blocks reduce 256 partials per feature ----------
    if (blk < 40) {
        float* psum = smem; float* psq = smem + 256;
        int fl = tid & 63, kl = tid >> 6;
        int f = blk * 64 + fl;
        float s = 0.f, q = 0.f;
        if (f < 2500) {
#pragma unroll 8
            for (int k = kl; k < 256; k += 4) {
                s += ws[P1S_OFF + (long)k * 2500 + f];
                q += ws[P1Q_OFF + (long)k * 2500 + f];
            }
        }
        psum[tid] = s; psq[tid] = q;
        __syncthreads();
        if (tid < 64 && f < 2500) {
            float ss = psum[tid] + psum[tid + 64] + psum[tid + 128] + psum[tid + 192];
            float qq = psq[tid]  + psq[tid + 64]  + psq[tid + 128]  + psq[tid + 192];
            float mean = ss * (1.f / 1024.f);
            float var  = qq * (1.f / 1024.f) - mean * mean;
            float a = grel[f] * rsqrtf(var + EPS);
            ws[REL_A + f] = a;
            ws[REL_B + f] = brel[f] - mean * a;
        }
    }
    grid.sync();   // S2

    // ---------- P1 conv: 512 blocks x 2 samples ----------
    {
        float* flt  = smem;          // 2500
        float* es   = smem + 2512;   // 100
        float* a0c0 = smem + 2616;   // 2
        if (tid == 0) {
            float s = 0.f, q = 0.f;
#pragma unroll
            for (int i = 0; i < 8; i++) { s += ws[EPART + 2 * i]; q += ws[EPART + 2 * i + 1]; }
            float mean = s * (1.f / 102400.f);
            float var  = q * (1.f / 102400.f) - mean * mean;
            float a = g0[0] * rsqrtf(var + EPS);
            a0c0[0] = a; a0c0[1] = b0[0] - mean * a;
        }
        __syncthreads();
        float a0 = a0c0[0], c0 = a0c0[1];
        for (int s5 = 0; s5 < 2; s5++) {
            int b = blk * 2 + s5;
            long ebase = (long)e1[b] * 100;
            for (int i = tid; i < 100; i += 256) es[i] = a0 * emb_e[ebase + i] + c0;
            long rbase = (long)rel[b] * 2500;
            for (int i = tid; i < 2500; i += 256) flt[i] = ws[REL_A + i] * emb_rel[rbase + i] + ws[REL_B + i];
            __syncthreads();
            for (int u = tid; u < 600; u += 256) {
                int f = u / 6, oi = u - f * 6;
                float er[5][10];
#pragma unroll
                for (int p = 0; p < 5; p++)
#pragma unroll
                    for (int c = 0; c < 10; c++) er[p][c] = es[(oi + p) * 10 + c];
                float fw[25];
#pragma unroll
                for (int k = 0; k < 25; k++) fw[k] = flt[f * 25 + k];
                float* dst = xbuf + (long)b * 3600 + f * 36 + oi * 6;
#pragma unroll
                for (int oj = 0; oj < 6; oj++) {
                    float acc = 0.f;
#pragma unroll
                    for (int p = 0; p < 5; p++)
#pragma unroll
                        for (int q = 0; q < 5; q++) acc += er[p][oj + q] * fw[p * 5 + q];
                    dst[oj] = acc;
                }
            }
            __syncthreads();
        }
    }
    grid.sync();   // S3

    // ---------- P2 bn1 partials: 400 blocks = (100 ch x 4 row-chunks) ----------
    if (blk < 400) {
        float* ps = smem; float* pq = smem + 256;
        int ch = blk >> 2, chunk = blk & 3;
        int rbase = chunk * 256;
        float s = 0.f, q = 0.f;
        for (int i = tid; i < 9216; i += 256) {
            int r = rbase + i / 36, o = i % 36;
            float v = xbuf[(long)r * 3600 + ch * 36 + o];
            s += v; q += v * v;
        }
        ps[tid] = s; pq[tid] = q;
        __syncthreads();
        for (int off = 128; off > 0; off >>= 1) {
            if (tid < off) { ps[tid] += ps[tid + off]; pq[tid] += pq[tid + off]; }
            __syncthreads();
        }
        if (tid == 0) { ws[P2S_OFF + chunk * 100 + ch] = ps[0]; ws[P2Q_OFF + chunk * 100 + ch] = pq[0]; }
    }
    grid.sync();   // S4

    // ---------- P3 FC: 512 blocks x 2 units (unit = (sb, kc)) ----------
    {
        float* a1s = smem;         // 100
        float* c1s = smem + 128;   // 100
        float (*xs)[900] = (float(*)[900])(smem + 256);  // 4x900
        if (tid < 100) {
            float s4 = ws[P2S_OFF + tid] + ws[P2S_OFF + 100 + tid] + ws[P2S_OFF + 200 + tid] + ws[P2S_OFF + 300 + tid];
            float q4 = ws[P2Q_OFF + tid] + ws[P2Q_OFF + 100 + tid] + ws[P2Q_OFF + 200 + tid] + ws[P2Q_OFF + 300 + tid];
            float mean = s4 * (1.f / 36864.f);
            float var  = q4 * (1.f / 36864.f) - mean * mean;
            float a = g1[tid] * rsqrtf(var + EPS);
            a1s[tid] = a; c1s[tid] = b1[tid] - mean * a;
        }
        __syncthreads();
        for (int uu = 0; uu < 2; uu++) {
            int u = blk * 2 + uu;
            int sb = u & 255, kc = u >> 8;
            int b0s = sb * 4, k0 = kc * 900;
            for (int idx = tid; idx < 3600; idx += 256) {
                int s = idx / 900, k = idx - s * 900;
                int kg = k0 + k;
                int f = kg / 36;
                float v = xbuf[(long)(b0s + s) * 3600 + kg];
                v = a1s[f] * v + c1s[f];
                xs[s][k] = v > 0.f ? v : 0.f;
            }
            __syncthreads();
            if (tid < 200) {
                int j = tid % 100, sg = tid / 100;
                float acc0 = 0.f, acc1 = 0.f;
                const float4* wrow = (const float4*)(fc_w + (long)j * 3600 + k0);
                const float4* x0 = (const float4*)(&xs[sg][0]);
                const float4* x1 = (const float4*)(&xs[sg + 2][0]);
#pragma unroll 5
                for (int kk = 0; kk < 225; kk++) {
                    float4 w4 = wrow[kk];
                    float4 a4 = x0[kk], b4 = x1[kk];
                    acc0 += w4.x * a4.x + w4.y * a4.y + w4.z * a4.z + w4.w * a4.w;
                    acc1 += w4.x * b4.x + w4.y * b4.y + w4.z * b4.z + w4.w * b4.w;
                }
                part[((long)kc * 1024 + b0s + sg) * 100 + j]     = acc0;
                part[((long)kc * 1024 + b0s + sg + 2) * 100 + j] = acc1;
            }
            __syncthreads();
        }
    }
    grid.sync();   // S5

    // ---------- P4 bn2 + xhat (bf16, K padded to 128): blocks 0..127 ----------
    if (blk < 128) {
        int j = blk;
        if (j >= 100) {
            for (int t = 0; t < 4; t++) xhat[(long)(tid + t * 256) * 128 + j] = 0;
            return;
        }
        float* ps = smem; float* pq = smem + 256; float* ab = smem + 512;
        float v[4];
        float s = 0.f, q = 0.f;
#pragma unroll
        for (int t = 0; t < 4; t++) {
            int b = tid + t * 256;
            float x = part[(long)b * 100 + j] + part[(long)(1024 + b) * 100 + j]
                    + part[(long)(2048 + b) * 100 + j] + part[(long)(3072 + b) * 100 + j]
                    + fc_b[j];
            v[t] = x; s += x; q += x * x;
        }
        ps[tid] = s; pq[tid] = q;
        __syncthreads();
        for (int off = 128; off > 0; off >>= 1) {
            if (tid < off) { ps[tid] += ps[tid + off]; pq[tid] += pq[tid + off]; }
            __syncthreads();
        }
        if (tid == 0) {
            float mean = ps[0] * (1.f / 1024.f);
            float var  = pq[0] * (1.f / 1024.f) - mean * mean;
            float a = g2[j] * rsqrtf(var + EPS);
            ab[0] = a; ab[1] = b2[j] - mean * a;
        }
        __syncthreads();
        float a = ab[0], c = ab[1];
#pragma unroll
        for (int t = 0; t < 4; t++) {
            float x = a * v[t] + c;
            x = x > 0.f ? x : 0.f;
            xhat[(long)(tid + t * 256) * 128 + j] = f2bf(x);
        }
    }
}

// ============ GEMM: logits = Xhat @ emb_e^T + bias, sigmoid ============
// One block per 128-ent N-tile; E staged ONCE in LDS; A-frags hoisted to regs;
// next-chunk X prefetch hides L2 latency under the epilogue.
__global__ void __launch_bounds__(256, 3)
k_gemm(const unsigned short* __restrict__ xhat, const float* __restrict__ emb_e,
       const float* __restrict__ bias, float* __restrict__ out) {
    __shared__ __align__(16) unsigned short Es[128 * 128];  // [row][col] bf16, byte ^= (row&7)<<4
    char* EsB = (char*)Es;
    int tid = threadIdx.x;
    int n0 = blockIdx.x * 128;

    // ---- stage E tile: 2 threads per row ----
    {
        int r = tid >> 1, p = tid & 1;
        int g = n0 + r;
        unsigned int rowb = (unsigned)r * 256u;
        unsigned int sw = ((unsigned)r & 7u) << 4;
        ushort4 z; z.x = z.y = z.z = z.w = 0;
        if (g < NENT) {
            const float4* src = (const float4*)(emb_e + (long)g * 100);
            for (int i = p; i < 25; i += 2) {
                float4 v = src[i];
                ushort4 h;
                h.x = f2bf(v.x); h.y = f2bf(v.y); h.z = f2bf(v.z); h.w = f2bf(v.w);
                *(ushort4*)(EsB + ((rowb + 8u * i) ^ sw)) = h;
            }
        } else {
            for (int i = p; i < 25; i += 2) *(ushort4*)(EsB + ((rowb + 8u * i) ^ sw)) = z;
        }
        for (int zz = p; zz < 7; zz += 2) *(ushort4*)(EsB + ((rowb + 200u + 8u * zz) ^ sw)) = z;
    }
    __syncthreads();

    int w = tid >> 6, l = tid & 63;
    int l15 = l & 15, l4 = l >> 4;

    // ---- hoist ALL A (E) fragments to registers: Af[ks][fe] ----
    bf16x8 Af[4][2];
#pragma unroll
    for (int fe = 0; fe < 2; fe++) {
        unsigned int r = (unsigned)(w * 32 + fe * 16 + l15);
        unsigned int base = r * 256u + (unsigned)(l4 * 16);
        unsigned int sw = (r & 7u) << 4;
#pragma unroll
        for (int ks = 0; ks < 4; ks++)
            Af[ks][fe] = *(const bf16x8*)(EsB + ((base + (unsigned)(ks * 64)) ^ sw));
    }

    // bias + validity + incremental store pointers per fe
    int gnb[2]; bool valid[2]; float4 bias4[2]; float* rowp[2];
#pragma unroll
    for (int fe = 0; fe < 2; fe++) {
        gnb[fe] = n0 + w * 32 + fe * 16 + l4 * 4;
        valid[fe] = gnb[fe] < NENT;
        bias4[fe] = valid[fe] ? *(const float4*)(bias + gnb[fe]) : float4{0.f, 0.f, 0.f, 0.f};
        rowp[fe] = out + (long)l15 * NENT + gnb[fe];
    }
    int xrow = l15 * 128 + l4 * 8;   // element offset into xhat

    // prefetch chunk 0, ks 0
    bf16x8 Bp[4];
#pragma unroll
    for (int fx = 0; fx < 4; fx++)
        Bp[fx] = *(const bf16x8*)(xhat + (long)(fx * 2048 + xrow));

    for (int chunk = 0; chunk < 16; ++chunk) {
        int m0 = chunk * 64;
        f32x4 acc[2][4];
#pragma unroll
        for (int fe = 0; fe < 2; fe++)
#pragma unroll
            for (int fx = 0; fx < 4; fx++) acc[fe][fx] = f32x4{0.f, 0.f, 0.f, 0.f};

        // ks = 0 from prefetch regs
#pragma unroll
        for (int fe = 0; fe < 2; fe++)
#pragma unroll
            for (int fx = 0; fx < 4; fx++)
                acc[fe][fx] = __builtin_amdgcn_mfma_f32_16x16x32_bf16(Af[0][fe], Bp[fx], acc[fe][fx], 0, 0, 0);

        // ks = 1..3
#pragma unroll
        for (int ks = 1; ks < 4; ++ks) {
            bf16x8 Bf[4];
#pragma unroll
            for (int fx = 0; fx < 4; fx++)
                Bf[fx] = *(const bf16x8*)(xhat + (long)(m0 * 128 + fx * 2048 + ks * 32 + xrow));
#pragma unroll
            for (int fe = 0; fe < 2; fe++)
#pragma unroll
                for (int fx = 0; fx < 4; fx++)
                    acc[fe][fx] = __builtin_amdgcn_mfma_f32_16x16x32_bf16(Af[ks][fe], Bf[fx], acc[fe][fx], 0, 0, 0);
        }

        // prefetch next chunk ks=0 (hidden under epilogue)
        if (chunk < 15) {
            int m0n = (chunk + 1) * 64;
#pragma unroll
            for (int fx = 0; fx < 4; fx++)
                Bp[fx] = *(const bf16x8*)(xhat + (long)(m0n * 128 + fx * 2048 + xrow));
        }

        // epilogue: + bias, sigmoid, float4 stores (incremental pointers)
#pragma unroll
        for (int fe = 0; fe < 2; fe++) {
            if (valid[fe]) {
                float* pr = rowp[fe];
#pragma unroll
                for (int fx = 0; fx < 4; fx++) {
                    float4 o;
#pragma unroll
                    for (int r2 = 0; r2 < 4; r2++) {
                        float x = acc[fe][fx][r2] + ((const float*)&bias4[fe])[r2];
                        float e = __builtin_amdgcn_exp2f(x * -1.44269504f);
                        ((float*)&o)[r2] = __builtin_amdgcn_rcpf(1.0f + e);
                    }
                    *(float4*)pr = o;
                    pr += (long)16 * NENT;
                }
            }
            rowp[fe] += (long)64 * NENT;
        }
    }
}

extern "C" void kernel_launch(void* const* d_in, const int* in_sizes, int n_in,
                              void* d_out, int out_size, void* d_ws, size_t ws_size,
                              hipStream_t stream) {
    const int*   e1      = (const int*)d_in[0];
    const int*   rel     = (const int*)d_in[1];
    const float* emb_e   = (const float*)d_in[2];
    const float* emb_rel = (const float*)d_in[3];
    const float* fc_w    = (const float*)d_in[4];
    const float* fc_b    = (const float*)d_in[5];
    const float* bias    = (const float*)d_in[6];
    const float* g0      = (const float*)d_in[7];
    const float* b0      = (const float*)d_in[8];
    const float* g1      = (const float*)d_in[9];
    const float* b1      = (const float*)d_in[10];
    const float* grel    = (const float*)d_in[11];
    const float* brel    = (const float*)d_in[12];
    const float* g2      = (const float*)d_in[13];
    const float* b2      = (const float*)d_in[14];
    float* ws  = (float*)d_ws;
    float* out = (float*)d_out;

    void* args[] = {(void*)&rel, (void*)&emb_rel, (void*)&grel, (void*)&brel,
                    (void*)&e1, (void*)&emb_e, (void*)&g0, (void*)&b0,
                    (void*)&g1, (void*)&b1, (void*)&fc_w, (void*)&fc_b,
                    (void*)&g2, (void*)&b2, (void*)&ws};
    hipLaunchCooperativeKernel((void*)k_pre, dim3(512), dim3(256), args, 0, stream);

    hipLaunchKernelGGL(k_gemm, dim3(782), dim3(256), 0, stream,
                       (const unsigned short*)(ws + XHAT_OFF), emb_e, bias, out);
}

// Round 5
// 285.239 us; speedup vs baseline: 2.1845x; 2.1845x over previous
//
#include <hip/hip_runtime.h>
#include <cstdint>

#define NENT 100000
#define EPS 1e-5f

// ---- ws layout (float offsets) ----
constexpr long REL_A    = 0;        // 2500
constexpr long REL_B    = 2500;     // 2500
constexpr long EPART    = 5000;     // 32 (16 blocks x {sum, sumsq})
constexpr long P2S_OFF  = 5056;     // 400 (4 chunks x 100 ch)
constexpr long P2Q_OFF  = 5456;     // 400
constexpr long PART_OFF = 5888;     // 4*1024*100 = 409600
constexpr long XBUF_OFF = 415488;   // 1024*3600  = 3686400
constexpr long XHAT_OFF = 4101888;  // 1024*128 bf16 = 65536 floats

typedef __attribute__((ext_vector_type(8))) __bf16 bf16x8;
typedef __attribute__((ext_vector_type(4))) float  f32x4;

__device__ __forceinline__ unsigned short f2bf(float f) {
    unsigned int u = __float_as_uint(f);
    unsigned int r = (u + 0x7FFFu + ((u >> 16) & 1u)) >> 16;
    return (unsigned short)r;
}

// K1: blocks 0..39  -> rel-BN stats via 500-bin histogram (emb_rel read ONCE, coalesced)
//     blocks 40..55 -> e-BN0 partial sums (16 blocks x 64 gathered rows)
__global__ void k_stats(const int* __restrict__ rel, const float* __restrict__ emb_rel,
                        const float* __restrict__ grel, const float* __restrict__ brel,
                        const int* __restrict__ e1, const float* __restrict__ emb_e,
                        float* __restrict__ ws) {
    int tid = threadIdx.x, blk = blockIdx.x;
    if (blk < 40) {
        __shared__ float cntf[512];
        __shared__ float ps[256], pq[256];
        int* cnti = (int*)cntf;
        for (int i = tid; i < 512; i += 256) cnti[i] = 0;
        __syncthreads();
        for (int i = tid; i < 1024; i += 256) atomicAdd(&cnti[rel[i]], 1);
        __syncthreads();
        for (int i = tid; i < 512; i += 256) cntf[i] = (float)cnti[i];
        __syncthreads();
        int f = blk * 64 + (tid & 63);
        int w = tid >> 6;           // wave handles rows w*125 .. w*125+124
        float s = 0.f, q = 0.f;
        if (f < 2500) {
            const float* base = emb_rel + (long)w * 125 * 2500 + f;
#pragma unroll 4
            for (int r = 0; r < 125; r++) {
                float c = cntf[w * 125 + r];      // wave-uniform broadcast
                if (c != 0.f) {
                    float v = base[(long)r * 2500];
                    s = fmaf(c, v, s);
                    q = fmaf(c * v, v, q);
                }
            }
        }
        ps[tid] = s; pq[tid] = q;
        __syncthreads();
        if (tid < 64 && f < 2500) {
            float ss = ps[tid] + ps[tid + 64] + ps[tid + 128] + ps[tid + 192];
            float qq = pq[tid] + pq[tid + 64] + pq[tid + 128] + pq[tid + 192];
            float mean = ss * (1.f / 1024.f);
            float var  = qq * (1.f / 1024.f) - mean * mean;
            float a = grel[f] * rsqrtf(var + EPS);
            ws[REL_A + f] = a;
            ws[REL_B + f] = brel[f] - mean * a;
        }
    } else if (blk < 56) {
        __shared__ int eidx[64];
        __shared__ float ps[256], pq[256];
        int bi = blk - 40;
        if (tid < 64) eidx[tid] = e1[bi * 64 + tid];
        __syncthreads();
        float s = 0.f, q = 0.f;
        for (int i = tid; i < 6400; i += 256) {
            int b = i / 100, d = i - b * 100;
            float v = emb_e[(long)eidx[b] * 100 + d];
            s += v; q += v * v;
        }
        ps[tid] = s; pq[tid] = q;
        __syncthreads();
        for (int off = 128; off > 0; off >>= 1) {
            if (tid < off) { ps[tid] += ps[tid + off]; pq[tid] += pq[tid + off]; }
            __syncthreads();
        }
        if (tid == 0) { ws[EPART + bi * 2] = ps[0]; ws[EPART + bi * 2 + 1] = pq[0]; }
    }
}

// K2: per-sample grouped conv 10x10 * (100 x 5x5) -> [B,100,6,6]
__global__ void k_conv(const int* __restrict__ e1, const int* __restrict__ rel,
                       const float* __restrict__ emb_e, const float* __restrict__ emb_rel,
                       const float* __restrict__ g0, const float* __restrict__ b0,
                       const float* __restrict__ ws, float* __restrict__ xout) {
    __shared__ float es[100];
    __shared__ float flt[2500];
    __shared__ float a0c0[2];
    int b = blockIdx.x, tid = threadIdx.x;
    if (tid == 0) {
        float s = 0.f, q = 0.f;
#pragma unroll
        for (int i = 0; i < 16; i++) { s += ws[EPART + 2 * i]; q += ws[EPART + 2 * i + 1]; }
        float mean = s * (1.f / 102400.f);
        float var  = q * (1.f / 102400.f) - mean * mean;
        float a = g0[0] * rsqrtf(var + EPS);
        a0c0[0] = a; a0c0[1] = b0[0] - mean * a;
    }
    __syncthreads();
    float a0 = a0c0[0], c0 = a0c0[1];
    long ebase = (long)e1[b] * 100;
    for (int i = tid; i < 100; i += 256) es[i] = a0 * emb_e[ebase + i] + c0;
    long rbase = (long)rel[b] * 2500;
    for (int i = tid; i < 2500; i += 256) flt[i] = ws[REL_A + i] * emb_rel[rbase + i] + ws[REL_B + i];
    __syncthreads();
    for (int u = tid; u < 600; u += 256) {
        int f = u / 6, oi = u - f * 6;
        float er[5][10];
#pragma unroll
        for (int p = 0; p < 5; p++)
#pragma unroll
            for (int c = 0; c < 10; c++) er[p][c] = es[(oi + p) * 10 + c];
        float fw[25];
#pragma unroll
        for (int k = 0; k < 25; k++) fw[k] = flt[f * 25 + k];
        float* dst = xout + (long)b * 3600 + f * 36 + oi * 6;
#pragma unroll
        for (int oj = 0; oj < 6; oj++) {
            float acc = 0.f;
#pragma unroll
            for (int p = 0; p < 5; p++)
#pragma unroll
                for (int q = 0; q < 5; q++) acc += er[p][oj + q] * fw[p * 5 + q];
            dst[oj] = acc;
        }
    }
}

// K3: per-channel BN1 partial stats: 400 blocks = (100 ch x 4 row-chunks)
__global__ void k_bn1p(const float* __restrict__ xbuf, float* __restrict__ ws) {
    __shared__ float ps[256], pq[256];
    int tid = threadIdx.x;
    int ch = blockIdx.x >> 2, chunk = blockIdx.x & 3;
    int rbase = chunk * 256;
    float s = 0.f, q = 0.f;
    for (int i = tid; i < 9216; i += 256) {
        int r = rbase + i / 36, o = i % 36;
        float v = xbuf[(long)r * 3600 + ch * 36 + o];
        s += v; q += v * v;
    }
    ps[tid] = s; pq[tid] = q;
    __syncthreads();
    for (int off = 128; off > 0; off >>= 1) {
        if (tid < off) { ps[tid] += ps[tid + off]; pq[tid] += pq[tid + off]; }
        __syncthreads();
    }
    if (tid == 0) { ws[P2S_OFF + chunk * 100 + ch] = ps[0]; ws[P2Q_OFF + chunk * 100 + ch] = pq[0]; }
}

// K4: FC partials (finalizes BN1 from partials in preamble). grid (256, 4)
__global__ void k_fc(const float* __restrict__ xbuf, const float* __restrict__ fc_w,
                     const float* __restrict__ g1, const float* __restrict__ b1,
                     const float* __restrict__ ws, float* __restrict__ part) {
    __shared__ float a1s[100], c1s[100];
    __shared__ float xs[4][900];
    int tid = threadIdx.x;
    int sb = blockIdx.x, kc = blockIdx.y;
    if (tid < 100) {
        float s4 = ws[P2S_OFF + tid] + ws[P2S_OFF + 100 + tid] + ws[P2S_OFF + 200 + tid] + ws[P2S_OFF + 300 + tid];
        float q4 = ws[P2Q_OFF + tid] + ws[P2Q_OFF + 100 + tid] + ws[P2Q_OFF + 200 + tid] + ws[P2Q_OFF + 300 + tid];
        float mean = s4 * (1.f / 36864.f);
        float var  = q4 * (1.f / 36864.f) - mean * mean;
        float a = g1[tid] * rsqrtf(var + EPS);
        a1s[tid] = a; c1s[tid] = b1[tid] - mean * a;
    }
    __syncthreads();
    int b0s = sb * 4, k0 = kc * 900;
    for (int idx = tid; idx < 3600; idx += 256) {
        int s = idx / 900, k = idx - s * 900;
        int kg = k0 + k;
        int f = kg / 36;
        float v = xbuf[(long)(b0s + s) * 3600 + kg];
        v = a1s[f] * v + c1s[f];
        xs[s][k] = v > 0.f ? v : 0.f;
    }
    __syncthreads();
    if (tid < 200) {
        int j = tid % 100, sg = tid / 100;
        float acc0 = 0.f, acc1 = 0.f;
        const float4* wrow = (const float4*)(fc_w + (long)j * 3600 + k0);
        const float4* x0 = (const float4*)(&xs[sg][0]);
        const float4* x1 = (const float4*)(&xs[sg + 2][0]);
#pragma unroll 5
        for (int kk = 0; kk < 225; kk++) {
            float4 w4 = wrow[kk];
            float4 a4 = x0[kk], b4 = x1[kk];
            acc0 += w4.x * a4.x + w4.y * a4.y + w4.z * a4.z + w4.w * a4.w;
            acc1 += w4.x * b4.x + w4.y * b4.y + w4.z * b4.z + w4.w * b4.w;
        }
        part[((long)kc * 1024 + b0s + sg) * 100 + j]     = acc0;
        part[((long)kc * 1024 + b0s + sg + 2) * 100 + j] = acc1;
    }
}

// K5: combine FC partials + fc_b, BN2 stats + apply + ReLU -> xhat bf16 [1024][128]
__global__ void k_bn2x(const float* __restrict__ part, const float* __restrict__ fc_b,
                       const float* __restrict__ g2, const float* __restrict__ b2,
                       unsigned short* __restrict__ xhat) {
    int j = blockIdx.x, tid = threadIdx.x;
    if (j >= 100) {
        for (int t = 0; t < 4; t++) xhat[(long)(tid + t * 256) * 128 + j] = 0;
        return;
    }
    __shared__ float ps[256], pq[256];
    __shared__ float ab[2];
    float v[4];
    float s = 0.f, q = 0.f;
#pragma unroll
    for (int t = 0; t < 4; t++) {
        int b = tid + t * 256;
        float x = part[(long)b * 100 + j] + part[(long)(1024 + b) * 100 + j]
                + part[(long)(2048 + b) * 100 + j] + part[(long)(3072 + b) * 100 + j]
                + fc_b[j];
        v[t] = x; s += x; q += x * x;
    }
    ps[tid] = s; pq[tid] = q;
    __syncthreads();
    for (int off = 128; off > 0; off >>= 1) {
        if (tid < off) { ps[tid] += ps[tid + off]; pq[tid] += pq[tid + off]; }
        __syncthreads();
    }
    if (tid == 0) {
        float mean = ps[0] * (1.f / 1024.f);
        float var  = pq[0] * (1.f / 1024.f) - mean * mean;
        float a = g2[j] * rsqrtf(var + EPS);
        ab[0] = a; ab[1] = b2[j] - mean * a;
    }
    __syncthreads();
    float a = ab[0], c = ab[1];
#pragma unroll
    for (int t = 0; t < 4; t++) {
        float x = a * v[t] + c;
        x = x > 0.f ? x : 0.f;
        xhat[(long)(tid + t * 256) * 128 + j] = f2bf(x);
    }
}

// K6: logits = Xhat @ emb_e^T + bias, sigmoid.  M=1024 N=100000 K=128(pad)
// E staged once in LDS -> A-frags hoisted to regs -> Es reused as f32 transpose
// buffer so stores are row-contiguous (2 x 512 B per wave-instr), nontemporal.
__global__ void __launch_bounds__(256, 3)
k_gemm(const unsigned short* __restrict__ xhat, const float* __restrict__ emb_e,
       const float* __restrict__ bias, float* __restrict__ out) {
    __shared__ __align__(16) unsigned short Es[128 * 128];  // 32 KB; later reused as float[64][128]
    __shared__ __align__(16) float bias_s[128];
    char* EsB = (char*)Es;
    int tid = threadIdx.x;
    int n0 = blockIdx.x * 128;

    // ---- stage E tile (bf16, byte ^= (row&7)<<4): 2 threads per row ----
    {
        int r = tid >> 1, p = tid & 1;
        int g = n0 + r;
        unsigned int rowb = (unsigned)r * 256u;
        unsigned int sw = ((unsigned)r & 7u) << 4;
        ushort4 z; z.x = z.y = z.z = z.w = 0;
        if (g < NENT) {
            const float4* src = (const float4*)(emb_e + (long)g * 100);
            for (int i = p; i < 25; i += 2) {
                float4 v = src[i];
                ushort4 h;
                h.x = f2bf(v.x); h.y = f2bf(v.y); h.z = f2bf(v.z); h.w = f2bf(v.w);
                *(ushort4*)(EsB + ((rowb + 8u * i) ^ sw)) = h;
            }
        } else {
            for (int i = p; i < 25; i += 2) *(ushort4*)(EsB + ((rowb + 8u * i) ^ sw)) = z;
        }
        for (int zz = p; zz < 7; zz += 2) *(ushort4*)(EsB + ((rowb + 200u + 8u * zz) ^ sw)) = z;
        if (tid < 32) {
            int c = n0 + tid * 4;
            *(float4*)&bias_s[tid * 4] = (c < NENT) ? *(const float4*)(bias + c)
                                                    : float4{0.f, 0.f, 0.f, 0.f};
        }
    }
    __syncthreads();

    int w = tid >> 6, l = tid & 63;
    int l15 = l & 15, l4 = l >> 4;

    // ---- hoist ALL A (E) fragments to registers: Af[ks][fe] ----
    bf16x8 Af[4][2];
#pragma unroll
    for (int fe = 0; fe < 2; fe++) {
        unsigned int r = (unsigned)(w * 32 + fe * 16 + l15);
        unsigned int base = r * 256u + (unsigned)(l4 * 16);
        unsigned int sw = (r & 7u) << 4;
#pragma unroll
        for (int ks = 0; ks < 4; ks++)
            Af[ks][fe] = *(const bf16x8*)(EsB + ((base + (unsigned)(ks * 64)) ^ sw));
    }
    __syncthreads();   // Es is dead as bf16 tile; reuse as f32 transpose buffer

    int xrow = l15 * 128 + l4 * 8;   // element offset into xhat

    // LDS write offsets for the transpose epilogue (float4-slot swizzle c4 ^ ((row&7)<<2))
    unsigned int wbyte[2][4];
#pragma unroll
    for (int fe = 0; fe < 2; fe++)
#pragma unroll
        for (int fx = 0; fx < 4; fx++) {
            unsigned int row = (unsigned)(fx * 16 + l15);
            unsigned int c4  = (unsigned)(w * 8 + fe * 4 + l4);
            wbyte[fe][fx] = row * 512u + ((c4 ^ ((row & 7u) << 2)) << 4);
        }
    // readback addressing: thread handles (row = pass*8 + tid>>5, c4 = tid&31)
    int rb_r = tid >> 5, rb_c4 = tid & 31;
    int colg = n0 + rb_c4 * 4;
    bool colv = colg < NENT;
    f32x4 bb = *(f32x4*)&bias_s[rb_c4 * 4];

    // prefetch chunk 0, ks 0
    bf16x8 Bp[4];
#pragma unroll
    for (int fx = 0; fx < 4; fx++)
        Bp[fx] = *(const bf16x8*)(xhat + (long)(fx * 2048 + xrow));

    for (int chunk = 0; chunk < 16; ++chunk) {
        int m0 = chunk * 64;
        f32x4 acc[2][4];
#pragma unroll
        for (int fe = 0; fe < 2; fe++)
#pragma unroll
            for (int fx = 0; fx < 4; fx++) acc[fe][fx] = f32x4{0.f, 0.f, 0.f, 0.f};

#pragma unroll
        for (int fe = 0; fe < 2; fe++)
#pragma unroll
            for (int fx = 0; fx < 4; fx++)
                acc[fe][fx] = __builtin_amdgcn_mfma_f32_16x16x32_bf16(Af[0][fe], Bp[fx], acc[fe][fx], 0, 0, 0);

#pragma unroll
        for (int ks = 1; ks < 4; ++ks) {
            bf16x8 Bf[4];
#pragma unroll
            for (int fx = 0; fx < 4; fx++)
                Bf[fx] = *(const bf16x8*)(xhat + (long)(m0 * 128 + fx * 2048 + ks * 32 + xrow));
#pragma unroll
            for (int fe = 0; fe < 2; fe++)
#pragma unroll
                for (int fx = 0; fx < 4; fx++)
                    acc[fe][fx] = __builtin_amdgcn_mfma_f32_16x16x32_bf16(Af[ks][fe], Bf[fx], acc[fe][fx], 0, 0, 0);
        }

        // prefetch next chunk ks=0 (hides under epilogue)
        if (chunk < 15) {
            int m0n = (chunk + 1) * 64;
#pragma unroll
            for (int fx = 0; fx < 4; fx++)
                Bp[fx] = *(const bf16x8*)(xhat + (long)(m0n * 128 + fx * 2048 + xrow));
        }

        // ---- transpose epilogue ----
#pragma unroll
        for (int fe = 0; fe < 2; fe++)
#pragma unroll
            for (int fx = 0; fx < 4; fx++)
                *(f32x4*)(EsB + wbyte[fe][fx]) = acc[fe][fx];
        __syncthreads();
#pragma unroll
        for (int pass = 0; pass < 8; pass++) {
            int r = pass * 8 + rb_r;
            f32x4 v = *(f32x4*)(EsB + (unsigned)r * 512u
                                + (((unsigned)rb_c4 ^ (((unsigned)r & 7u) << 2)) << 4));
            f32x4 o;
#pragma unroll
            for (int k = 0; k < 4; k++) {
                float x = v[k] + bb[k];
                float e = __builtin_amdgcn_exp2f(x * -1.44269504f);
                o[k] = __builtin_amdgcn_rcpf(1.0f + e);
            }
            if (colv)
                __builtin_nontemporal_store(o, (f32x4*)(out + (long)(m0 + r) * NENT + colg));
        }
        __syncthreads();
    }
}

extern "C" void kernel_launch(void* const* d_in, const int* in_sizes, int n_in,
                              void* d_out, int out_size, void* d_ws, size_t ws_size,
                              hipStream_t stream) {
    const int*   e1      = (const int*)d_in[0];
    const int*   rel     = (const int*)d_in[1];
    const float* emb_e   = (const float*)d_in[2];
    const float* emb_rel = (const float*)d_in[3];
    const float* fc_w    = (const float*)d_in[4];
    const float* fc_b    = (const float*)d_in[5];
    const float* bias    = (const float*)d_in[6];
    const float* g0      = (const float*)d_in[7];
    const float* b0      = (const float*)d_in[8];
    const float* g1      = (const float*)d_in[9];
    const float* b1      = (const float*)d_in[10];
    const float* grel    = (const float*)d_in[11];
    const float* brel    = (const float*)d_in[12];
    const float* g2      = (const float*)d_in[13];
    const float* b2      = (const float*)d_in[14];
    float* ws  = (float*)d_ws;
    float* out = (float*)d_out;

    hipLaunchKernelGGL(k_stats, dim3(56), dim3(256), 0, stream, rel, emb_rel, grel, brel, e1, emb_e, ws);
    hipLaunchKernelGGL(k_conv, dim3(1024), dim3(256), 0, stream, e1, rel, emb_e, emb_rel, g0, b0, ws, ws + XBUF_OFF);
    hipLaunchKernelGGL(k_bn1p, dim3(400), dim3(256), 0, stream, ws + XBUF_OFF, ws);
    hipLaunchKernelGGL(k_fc, dim3(256, 4), dim3(256), 0, stream, ws + XBUF_OFF, fc_w, g1, b1, ws, ws + PART_OFF);
    hipLaunchKernelGGL(k_bn2x, dim3(128), dim3(256), 0, stream, ws + PART_OFF, fc_b, g2, b2,
                       (unsigned short*)(ws + XHAT_OFF));
    hipLaunchKernelGGL(k_gemm, dim3(782), dim3(256), 0, stream,
                       (const unsigned short*)(ws + XHAT_OFF), emb_e, bias, out);
}

// Round 6
// 260.097 us; speedup vs baseline: 2.3957x; 1.0967x over previous
//
#include <hip/hip_runtime.h>
#include <cstdint>

#define NENT 100000
#define EPS 1e-5f

// ---- ws layout (float offsets) ----
constexpr long REL_A    = 0;        // 2500
constexpr long REL_B    = 2500;     // 2500
constexpr long EPART    = 5000;     // 32 (16 blocks x {sum, sumsq})
constexpr long A1O      = 5056;     // 100
constexpr long C1O      = 5156;     // 100
constexpr long PART_OFF = 5888;     // 4*1024*100 = 409600  (also hosts conv bn1-partials [1024][200] early)
constexpr long XBUF_OFF = 415488;   // 1024*3600  = 3686400
constexpr long XHAT_OFF = 4101888;  // 1024*128 bf16 = 65536 floats

typedef __attribute__((ext_vector_type(8))) __bf16 bf16x8;
typedef __attribute__((ext_vector_type(4))) float  f32x4;

__device__ __forceinline__ unsigned short f2bf(float f) {
    unsigned int u = __float_as_uint(f);
    unsigned int r = (u + 0x7FFFu + ((u >> 16) & 1u)) >> 16;
    return (unsigned short)r;
}

// K1 (512 thr): blocks 0..39  -> rel-BN stats via 500-bin histogram (emb_rel read ONCE, 8-wave row split)
//               blocks 40..55 -> e-BN0 partial sums (16 blocks x 64 gathered rows)
__global__ void k_stats(const int* __restrict__ rel, const float* __restrict__ emb_rel,
                        const float* __restrict__ grel, const float* __restrict__ brel,
                        const int* __restrict__ e1, const float* __restrict__ emb_e,
                        float* __restrict__ ws) {
    __shared__ float cntf[512];
    __shared__ float ps[512], pq[512];
    int tid = threadIdx.x, blk = blockIdx.x;
    if (blk < 40) {
        int* cnti = (int*)cntf;
        cnti[tid] = 0;
        __syncthreads();
        for (int i = tid; i < 1024; i += 512) atomicAdd(&cnti[rel[i]], 1);
        __syncthreads();
        cntf[tid] = (float)cnti[tid];
        __syncthreads();
        int f = blk * 64 + (tid & 63);
        int w = tid >> 6;           // 8 waves, rows strided by 8
        float s = 0.f, q = 0.f;
        const float* base = emb_rel + f;
#pragma unroll 4
        for (int r = w; r < 500; r += 8) {
            float c = cntf[r];      // wave-uniform broadcast
            if (c != 0.f) {
                float v = base[(long)r * 2500];
                s = fmaf(c, v, s);
                q = fmaf(c * v, v, q);
            }
        }
        ps[tid] = s; pq[tid] = q;
        __syncthreads();
        if (tid < 64) {
            float ss = 0.f, qq = 0.f;
#pragma unroll
            for (int k = 0; k < 8; k++) { ss += ps[tid + k * 64]; qq += pq[tid + k * 64]; }
            float mean = ss * (1.f / 1024.f);
            float var  = qq * (1.f / 1024.f) - mean * mean;
            float a = grel[f] * rsqrtf(var + EPS);
            ws[REL_A + f] = a;
            ws[REL_B + f] = brel[f] - mean * a;
        }
    } else if (blk < 56) {
        int* eidx = (int*)cntf;
        int bi = blk - 40;
        if (tid < 64) eidx[tid] = e1[bi * 64 + tid];
        __syncthreads();
        float s = 0.f, q = 0.f;
        for (int i = tid; i < 6400; i += 512) {
            int b = i / 100, d = i - b * 100;
            float v = emb_e[(long)eidx[b] * 100 + d];
            s += v; q += v * v;
        }
        ps[tid] = s; pq[tid] = q;
        __syncthreads();
        for (int off = 256; off > 0; off >>= 1) {
            if (tid < off) { ps[tid] += ps[tid + off]; pq[tid] += pq[tid + off]; }
            __syncthreads();
        }
        if (tid == 0) { ws[EPART + bi * 2] = ps[0]; ws[EPART + bi * 2 + 1] = pq[0]; }
    }
}

// K2: per-sample grouped conv 10x10 * (100 x 5x5) -> [B,100,6,6]; emits per-channel
//     (sum,sumsq) partials for BN1 into part region [b][200]
__global__ void k_conv(const int* __restrict__ e1, const int* __restrict__ rel,
                       const float* __restrict__ emb_e, const float* __restrict__ emb_rel,
                       const float* __restrict__ g0, const float* __restrict__ b0,
                       const float* __restrict__ ws, float* __restrict__ xout,
                       float* __restrict__ bn1part) {
    __shared__ float es[100];
    __shared__ float flt[2500];
    __shared__ float a0c0[2];
    __shared__ float prs[600], prq[600];
    int b = blockIdx.x, tid = threadIdx.x;
    if (tid == 0) {
        float s = 0.f, q = 0.f;
#pragma unroll
        for (int i = 0; i < 16; i++) { s += ws[EPART + 2 * i]; q += ws[EPART + 2 * i + 1]; }
        float mean = s * (1.f / 102400.f);
        float var  = q * (1.f / 102400.f) - mean * mean;
        float a = g0[0] * rsqrtf(var + EPS);
        a0c0[0] = a; a0c0[1] = b0[0] - mean * a;
    }
    __syncthreads();
    float a0 = a0c0[0], c0 = a0c0[1];
    long ebase = (long)e1[b] * 100;
    for (int i = tid; i < 100; i += 256) es[i] = a0 * emb_e[ebase + i] + c0;
    long rbase = (long)rel[b] * 2500;
    for (int i = tid; i < 2500; i += 256) flt[i] = ws[REL_A + i] * emb_rel[rbase + i] + ws[REL_B + i];
    __syncthreads();
    for (int u = tid; u < 600; u += 256) {
        int f = u / 6, oi = u - f * 6;
        float er[5][10];
#pragma unroll
        for (int p = 0; p < 5; p++)
#pragma unroll
            for (int c = 0; c < 10; c++) er[p][c] = es[(oi + p) * 10 + c];
        float fw[25];
#pragma unroll
        for (int k = 0; k < 25; k++) fw[k] = flt[f * 25 + k];
        float* dst = xout + (long)b * 3600 + f * 36 + oi * 6;
        float s6 = 0.f, q6 = 0.f;
#pragma unroll
        for (int oj = 0; oj < 6; oj++) {
            float acc = 0.f;
#pragma unroll
            for (int p = 0; p < 5; p++)
#pragma unroll
                for (int q = 0; q < 5; q++) acc += er[p][oj + q] * fw[p * 5 + q];
            dst[oj] = acc;
            s6 += acc; q6 = fmaf(acc, acc, q6);
        }
        prs[u] = s6; prq[u] = q6;
    }
    __syncthreads();
    if (tid < 100) {
        float s = 0.f, q = 0.f;
#pragma unroll
        for (int k = 0; k < 6; k++) { s += prs[tid * 6 + k]; q += prq[tid * 6 + k]; }
        bn1part[(long)b * 200 + tid]       = s;
        bn1part[(long)b * 200 + 100 + tid] = q;
    }
}

// K3: reduce BN1 partials over 1024 blocks -> a1s/c1s (tiny, L2-resident)
__global__ void k_bn1r(const float* __restrict__ bn1part, const float* __restrict__ g1,
                       const float* __restrict__ b1, float* __restrict__ ws) {
    __shared__ float ps[256], pq[256];
    int f = blockIdx.x, tid = threadIdx.x;
    float s = 0.f, q = 0.f;
    for (int b = tid; b < 1024; b += 256) {
        s += bn1part[(long)b * 200 + f];
        q += bn1part[(long)b * 200 + 100 + f];
    }
    ps[tid] = s; pq[tid] = q;
    __syncthreads();
    for (int off = 128; off > 0; off >>= 1) {
        if (tid < off) { ps[tid] += ps[tid + off]; pq[tid] += pq[tid + off]; }
        __syncthreads();
    }
    if (tid == 0) {
        float mean = ps[0] * (1.f / 36864.f);
        float var  = pq[0] * (1.f / 36864.f) - mean * mean;
        float a = g1[f] * rsqrtf(var + EPS);
        ws[A1O + f] = a;
        ws[C1O + f] = b1[f] - mean * a;
    }
}

// K4: FC partials (BN1 already finalized). grid (256, 4)
__global__ void k_fc(const float* __restrict__ xbuf, const float* __restrict__ fc_w,
                     const float* __restrict__ ws, float* __restrict__ part) {
    __shared__ float a1s[100], c1s[100];
    __shared__ float xs[4][900];
    int tid = threadIdx.x;
    int sb = blockIdx.x, kc = blockIdx.y;
    if (tid < 100) { a1s[tid] = ws[A1O + tid]; c1s[tid] = ws[C1O + tid]; }
    __syncthreads();
    int b0s = sb * 4, k0 = kc * 900;
    for (int idx = tid; idx < 3600; idx += 256) {
        int s = idx / 900, k = idx - s * 900;
        int kg = k0 + k;
        int f = kg / 36;
        float v = xbuf[(long)(b0s + s) * 3600 + kg];
        v = a1s[f] * v + c1s[f];
        xs[s][k] = v > 0.f ? v : 0.f;
    }
    __syncthreads();
    if (tid < 200) {
        int j = tid % 100, sg = tid / 100;
        float acc0 = 0.f, acc1 = 0.f;
        const float4* wrow = (const float4*)(fc_w + (long)j * 3600 + k0);
        const float4* x0 = (const float4*)(&xs[sg][0]);
        const float4* x1 = (const float4*)(&xs[sg + 2][0]);
#pragma unroll 5
        for (int kk = 0; kk < 225; kk++) {
            float4 w4 = wrow[kk];
            float4 a4 = x0[kk], b4 = x1[kk];
            acc0 += w4.x * a4.x + w4.y * a4.y + w4.z * a4.z + w4.w * a4.w;
            acc1 += w4.x * b4.x + w4.y * b4.y + w4.z * b4.z + w4.w * b4.w;
        }
        part[((long)kc * 1024 + b0s + sg) * 100 + j]     = acc0;
        part[((long)kc * 1024 + b0s + sg + 2) * 100 + j] = acc1;
    }
}

// K5: combine FC partials + fc_b, BN2 stats + apply + ReLU -> xhat bf16 [1024][128]
__global__ void k_bn2x(const float* __restrict__ part, const float* __restrict__ fc_b,
                       const float* __restrict__ g2, const float* __restrict__ b2,
                       unsigned short* __restrict__ xhat) {
    int j = blockIdx.x, tid = threadIdx.x;
    if (j >= 100) {
        for (int t = 0; t < 4; t++) xhat[(long)(tid + t * 256) * 128 + j] = 0;
        return;
    }
    __shared__ float ps[256], pq[256];
    __shared__ float ab[2];
    float v[4];
    float s = 0.f, q = 0.f;
#pragma unroll
    for (int t = 0; t < 4; t++) {
        int b = tid + t * 256;
        float x = part[(long)b * 100 + j] + part[(long)(1024 + b) * 100 + j]
                + part[(long)(2048 + b) * 100 + j] + part[(long)(3072 + b) * 100 + j]
                + fc_b[j];
        v[t] = x; s += x; q += x * x;
    }
    ps[tid] = s; pq[tid] = q;
    __syncthreads();
    for (int off = 128; off > 0; off >>= 1) {
        if (tid < off) { ps[tid] += ps[tid + off]; pq[tid] += pq[tid + off]; }
        __syncthreads();
    }
    if (tid == 0) {
        float mean = ps[0] * (1.f / 1024.f);
        float var  = pq[0] * (1.f / 1024.f) - mean * mean;
        float a = g2[j] * rsqrtf(var + EPS);
        ab[0] = a; ab[1] = b2[j] - mean * a;
    }
    __syncthreads();
    float a = ab[0], c = ab[1];
#pragma unroll
    for (int t = 0; t < 4; t++) {
        float x = a * v[t] + c;
        x = x > 0.f ? x : 0.f;
        xhat[(long)(tid + t * 256) * 128 + j] = f2bf(x);
    }
}

// K6: logits = Xhat @ emb_e^T + bias, sigmoid.  M=1024 N=100000 K=128(pad)
// 4 blocks/CU -> all 782 blocks co-resident (no tail). E staged once; A-frags in regs;
// f32 transpose epilogue in reused LDS -> contiguous 512B nontemporal row stores.
__global__ void __launch_bounds__(256, 4)
k_gemm(const unsigned short* __restrict__ xhat, const float* __restrict__ emb_e,
       const float* __restrict__ bias, float* __restrict__ out) {
    __shared__ __align__(16) unsigned short Es[128 * 128];  // 32 KB; later reused as float[64][128]
    __shared__ __align__(16) float bias_s[128];
    char* EsB = (char*)Es;
    int tid = threadIdx.x;
    int n0 = blockIdx.x * 128;

    // ---- stage E tile (bf16, byte ^= (row&7)<<4): 2 threads per row ----
    {
        int r = tid >> 1, p = tid & 1;
        int g = n0 + r;
        unsigned int rowb = (unsigned)r * 256u;
        unsigned int sw = ((unsigned)r & 7u) << 4;
        ushort4 z; z.x = z.y = z.z = z.w = 0;
        if (g < NENT) {
            const float4* src = (const float4*)(emb_e + (long)g * 100);
            for (int i = p; i < 25; i += 2) {
                float4 v = src[i];
                ushort4 h;
                h.x = f2bf(v.x); h.y = f2bf(v.y); h.z = f2bf(v.z); h.w = f2bf(v.w);
                *(ushort4*)(EsB + ((rowb + 8u * i) ^ sw)) = h;
            }
        } else {
            for (int i = p; i < 25; i += 2) *(ushort4*)(EsB + ((rowb + 8u * i) ^ sw)) = z;
        }
        for (int zz = p; zz < 7; zz += 2) *(ushort4*)(EsB + ((rowb + 200u + 8u * zz) ^ sw)) = z;
        if (tid < 32) {
            int c = n0 + tid * 4;
            *(float4*)&bias_s[tid * 4] = (c < NENT) ? *(const float4*)(bias + c)
                                                    : float4{0.f, 0.f, 0.f, 0.f};
        }
    }
    __syncthreads();

    int w = tid >> 6, l = tid & 63;
    int l15 = l & 15, l4 = l >> 4;

    // ---- hoist ALL A (E) fragments to registers: Af[ks][fe] ----
    bf16x8 Af[4][2];
#pragma unroll
    for (int fe = 0; fe < 2; fe++) {
        unsigned int r = (unsigned)(w * 32 + fe * 16 + l15);
        unsigned int base = r * 256u + (unsigned)(l4 * 16);
        unsigned int sw = (r & 7u) << 4;
#pragma unroll
        for (int ks = 0; ks < 4; ks++)
            Af[ks][fe] = *(const bf16x8*)(EsB + ((base + (unsigned)(ks * 64)) ^ sw));
    }
    __syncthreads();   // Es is dead as bf16 tile; reuse as f32 transpose buffer

    int xrow = l15 * 128 + l4 * 8;   // element offset into xhat

    // LDS write offsets for the transpose epilogue (float4-slot swizzle c4 ^ ((row&7)<<2))
    unsigned int wbyte[2][4];
#pragma unroll
    for (int fe = 0; fe < 2; fe++)
#pragma unroll
        for (int fx = 0; fx < 4; fx++) {
            unsigned int row = (unsigned)(fx * 16 + l15);
            unsigned int c4  = (unsigned)(w * 8 + fe * 4 + l4);
            wbyte[fe][fx] = row * 512u + ((c4 ^ ((row & 7u) << 2)) << 4);
        }
    // readback addressing: thread handles (row = pass*8 + tid>>5, c4 = tid&31)
    int rb_r = tid >> 5, rb_c4 = tid & 31;
    int colg = n0 + rb_c4 * 4;
    bool colv = colg < NENT;
    f32x4 bb = *(f32x4*)&bias_s[rb_c4 * 4];

    // prefetch chunk 0, ks 0
    bf16x8 Bp[4];
#pragma unroll
    for (int fx = 0; fx < 4; fx++)
        Bp[fx] = *(const bf16x8*)(xhat + (long)(fx * 2048 + xrow));

    for (int chunk = 0; chunk < 16; ++chunk) {
        int m0 = chunk * 64;
        f32x4 acc[2][4];
#pragma unroll
        for (int fe = 0; fe < 2; fe++)
#pragma unroll
            for (int fx = 0; fx < 4; fx++) acc[fe][fx] = f32x4{0.f, 0.f, 0.f, 0.f};

#pragma unroll
        for (int fe = 0; fe < 2; fe++)
#pragma unroll
            for (int fx = 0; fx < 4; fx++)
                acc[fe][fx] = __builtin_amdgcn_mfma_f32_16x16x32_bf16(Af[0][fe], Bp[fx], acc[fe][fx], 0, 0, 0);

#pragma unroll
        for (int ks = 1; ks < 4; ++ks) {
            bf16x8 Bf[4];
#pragma unroll
            for (int fx = 0; fx < 4; fx++)
                Bf[fx] = *(const bf16x8*)(xhat + (long)(m0 * 128 + fx * 2048 + ks * 32 + xrow));
#pragma unroll
            for (int fe = 0; fe < 2; fe++)
#pragma unroll
                for (int fx = 0; fx < 4; fx++)
                    acc[fe][fx] = __builtin_amdgcn_mfma_f32_16x16x32_bf16(Af[ks][fe], Bf[fx], acc[fe][fx], 0, 0, 0);
        }

        // prefetch next chunk ks=0 (hides under epilogue)
        if (chunk < 15) {
            int m0n = (chunk + 1) * 64;
#pragma unroll
            for (int fx = 0; fx < 4; fx++)
                Bp[fx] = *(const bf16x8*)(xhat + (long)(m0n * 128 + fx * 2048 + xrow));
        }

        // ---- transpose epilogue ----
#pragma unroll
        for (int fe = 0; fe < 2; fe++)
#pragma unroll
            for (int fx = 0; fx < 4; fx++)
                *(f32x4*)(EsB + wbyte[fe][fx]) = acc[fe][fx];
        __syncthreads();
#pragma unroll
        for (int pass = 0; pass < 8; pass++) {
            int r = pass * 8 + rb_r;
            f32x4 v = *(f32x4*)(EsB + (unsigned)r * 512u
                                + (((unsigned)rb_c4 ^ (((unsigned)r & 7u) << 2)) << 4));
            f32x4 o;
#pragma unroll
            for (int k = 0; k < 4; k++) {
                float x = v[k] + bb[k];
                float e = __builtin_amdgcn_exp2f(x * -1.44269504f);
                o[k] = __builtin_amdgcn_rcpf(1.0f + e);
            }
            if (colv)
                __builtin_nontemporal_store(o, (f32x4*)(out + (long)(m0 + r) * NENT + colg));
        }
        __syncthreads();
    }
}

extern "C" void kernel_launch(void* const* d_in, const int* in_sizes, int n_in,
                              void* d_out, int out_size, void* d_ws, size_t ws_size,
                              hipStream_t stream) {
    const int*   e1      = (const int*)d_in[0];
    const int*   rel     = (const int*)d_in[1];
    const float* emb_e   = (const float*)d_in[2];
    const float* emb_rel = (const float*)d_in[3];
    const float* fc_w    = (const float*)d_in[4];
    const float* fc_b    = (const float*)d_in[5];
    const float* bias    = (const float*)d_in[6];
    const float* g0      = (const float*)d_in[7];
    const float* b0      = (const float*)d_in[8];
    const float* g1      = (const float*)d_in[9];
    const float* b1      = (const float*)d_in[10];
    const float* grel    = (const float*)d_in[11];
    const float* brel    = (const float*)d_in[12];
    const float* g2      = (const float*)d_in[13];
    const float* b2      = (const float*)d_in[14];
    float* ws  = (float*)d_ws;
    float* out = (float*)d_out;

    hipLaunchKernelGGL(k_stats, dim3(56), dim3(512), 0, stream, rel, emb_rel, grel, brel, e1, emb_e, ws);
    hipLaunchKernelGGL(k_conv, dim3(1024), dim3(256), 0, stream, e1, rel, emb_e, emb_rel, g0, b0,
                       ws, ws + XBUF_OFF, ws + PART_OFF);
    hipLaunchKernelGGL(k_bn1r, dim3(100), dim3(256), 0, stream, ws + PART_OFF, g1, b1, ws);
    hipLaunchKernelGGL(k_fc, dim3(256, 4), dim3(256), 0, stream, ws + XBUF_OFF, fc_w, ws, ws + PART_OFF);
    hipLaunchKernelGGL(k_bn2x, dim3(128), dim3(256), 0, stream, ws + PART_OFF, fc_b, g2, b2,
                       (unsigned short*)(ws + XHAT_OFF));
    hipLaunchKernelGGL(k_gemm, dim3(782), dim3(256), 0, stream,
                       (const unsigned short*)(ws + XHAT_OFF), emb_e, bias, out);
}

// Round 7
// 259.142 us; speedup vs baseline: 2.4045x; 1.0037x over previous
//
#include <hip/hip_runtime.h>
#include <cstdint>

#define NENT 100000
#define EPS 1e-5f

// ---- ws layout (float offsets) ----
constexpr long REL_A    = 0;        // 2500
constexpr long REL_B    = 2500;     // 2500
constexpr long EPART    = 5000;     // 32 (16 blocks x {sum, sumsq})
constexpr long A1O      = 5056;     // 100
constexpr long C1O      = 5156;     // 100
constexpr long PART_OFF = 5888;     // 4*1024*100 = 409600  (also hosts conv bn1-partials [1024][200] early)
constexpr long XBUF_OFF = 415488;   // 1024*3600  = 3686400
constexpr long XHAT_OFF = 4101888;  // 1024*128 bf16 = 65536 floats

typedef __attribute__((ext_vector_type(8))) __bf16 bf16x8;
typedef __attribute__((ext_vector_type(4))) float  f32x4;

__device__ __forceinline__ unsigned short f2bf(float f) {
    unsigned int u = __float_as_uint(f);
    unsigned int r = (u + 0x7FFFu + ((u >> 16) & 1u)) >> 16;
    return (unsigned short)r;
}

// K1 (512 thr): blocks 0..39  -> rel-BN stats via 500-bin histogram (emb_rel read ONCE, 8-wave row split)
//               blocks 40..55 -> e-BN0 partial sums (16 blocks x 64 gathered rows)
__global__ void k_stats(const int* __restrict__ rel, const float* __restrict__ emb_rel,
                        const float* __restrict__ grel, const float* __restrict__ brel,
                        const int* __restrict__ e1, const float* __restrict__ emb_e,
                        float* __restrict__ ws) {
    __shared__ float cntf[512];
    __shared__ float ps[512], pq[512];
    int tid = threadIdx.x, blk = blockIdx.x;
    if (blk < 40) {
        int* cnti = (int*)cntf;
        cnti[tid] = 0;
        __syncthreads();
        for (int i = tid; i < 1024; i += 512) atomicAdd(&cnti[rel[i]], 1);
        __syncthreads();
        cntf[tid] = (float)cnti[tid];
        __syncthreads();
        int f = blk * 64 + (tid & 63);
        int w = tid >> 6;           // 8 waves, rows strided by 8
        float s = 0.f, q = 0.f;
        const float* base = emb_rel + f;
#pragma unroll 4
        for (int r = w; r < 500; r += 8) {
            float c = cntf[r];      // wave-uniform broadcast
            if (c != 0.f) {
                float v = base[(long)r * 2500];
                s = fmaf(c, v, s);
                q = fmaf(c * v, v, q);
            }
        }
        ps[tid] = s; pq[tid] = q;
        __syncthreads();
        if (tid < 64) {
            float ss = 0.f, qq = 0.f;
#pragma unroll
            for (int k = 0; k < 8; k++) { ss += ps[tid + k * 64]; qq += pq[tid + k * 64]; }
            float mean = ss * (1.f / 1024.f);
            float var  = qq * (1.f / 1024.f) - mean * mean;
            float a = grel[f] * rsqrtf(var + EPS);
            ws[REL_A + f] = a;
            ws[REL_B + f] = brel[f] - mean * a;
        }
    } else if (blk < 56) {
        int* eidx = (int*)cntf;
        int bi = blk - 40;
        if (tid < 64) eidx[tid] = e1[bi * 64 + tid];
        __syncthreads();
        float s = 0.f, q = 0.f;
        for (int i = tid; i < 6400; i += 512) {
            int b = i / 100, d = i - b * 100;
            float v = emb_e[(long)eidx[b] * 100 + d];
            s += v; q += v * v;
        }
        ps[tid] = s; pq[tid] = q;
        __syncthreads();
        for (int off = 256; off > 0; off >>= 1) {
            if (tid < off) { ps[tid] += ps[tid + off]; pq[tid] += pq[tid + off]; }
            __syncthreads();
        }
        if (tid == 0) { ws[EPART + bi * 2] = ps[0]; ws[EPART + bi * 2 + 1] = pq[0]; }
    }
}

// K2: per-sample grouped conv 10x10 * (100 x 5x5) -> [B,100,6,6]; emits per-channel
//     (sum,sumsq) partials for BN1 into part region [b][200]
__global__ void k_conv(const int* __restrict__ e1, const int* __restrict__ rel,
                       const float* __restrict__ emb_e, const float* __restrict__ emb_rel,
                       const float* __restrict__ g0, const float* __restrict__ b0,
                       const float* __restrict__ ws, float* __restrict__ xout,
                       float* __restrict__ bn1part) {
    __shared__ float es[100];
    __shared__ float flt[2500];
    __shared__ float a0c0[2];
    __shared__ float prs[600], prq[600];
    int b = blockIdx.x, tid = threadIdx.x;
    if (tid == 0) {
        float s = 0.f, q = 0.f;
#pragma unroll
        for (int i = 0; i < 16; i++) { s += ws[EPART + 2 * i]; q += ws[EPART + 2 * i + 1]; }
        float mean = s * (1.f / 102400.f);
        float var  = q * (1.f / 102400.f) - mean * mean;
        float a = g0[0] * rsqrtf(var + EPS);
        a0c0[0] = a; a0c0[1] = b0[0] - mean * a;
    }
    __syncthreads();
    float a0 = a0c0[0], c0 = a0c0[1];
    long ebase = (long)e1[b] * 100;
    for (int i = tid; i < 100; i += 256) es[i] = a0 * emb_e[ebase + i] + c0;
    long rbase = (long)rel[b] * 2500;
    for (int i = tid; i < 2500; i += 256) flt[i] = ws[REL_A + i] * emb_rel[rbase + i] + ws[REL_B + i];
    __syncthreads();
    for (int u = tid; u < 600; u += 256) {
        int f = u / 6, oi = u - f * 6;
        float er[5][10];
#pragma unroll
        for (int p = 0; p < 5; p++)
#pragma unroll
            for (int c = 0; c < 10; c++) er[p][c] = es[(oi + p) * 10 + c];
        float fw[25];
#pragma unroll
        for (int k = 0; k < 25; k++) fw[k] = flt[f * 25 + k];
        float* dst = xout + (long)b * 3600 + f * 36 + oi * 6;
        float s6 = 0.f, q6 = 0.f;
#pragma unroll
        for (int oj = 0; oj < 6; oj++) {
            float acc = 0.f;
#pragma unroll
            for (int p = 0; p < 5; p++)
#pragma unroll
                for (int q = 0; q < 5; q++) acc += er[p][oj + q] * fw[p * 5 + q];
            dst[oj] = acc;
            s6 += acc; q6 = fmaf(acc, acc, q6);
        }
        prs[u] = s6; prq[u] = q6;
    }
    __syncthreads();
    if (tid < 100) {
        float s = 0.f, q = 0.f;
#pragma unroll
        for (int k = 0; k < 6; k++) { s += prs[tid * 6 + k]; q += prq[tid * 6 + k]; }
        bn1part[(long)b * 200 + tid]       = s;
        bn1part[(long)b * 200 + 100 + tid] = q;
    }
}

// K3: reduce BN1 partials over 1024 blocks -> a1s/c1s (tiny, L2-resident)
__global__ void k_bn1r(const float* __restrict__ bn1part, const float* __restrict__ g1,
                       const float* __restrict__ b1, float* __restrict__ ws) {
    __shared__ float ps[256], pq[256];
    int f = blockIdx.x, tid = threadIdx.x;
    float s = 0.f, q = 0.f;
    for (int b = tid; b < 1024; b += 256) {
        s += bn1part[(long)b * 200 + f];
        q += bn1part[(long)b * 200 + 100 + f];
    }
    ps[tid] = s; pq[tid] = q;
    __syncthreads();
    for (int off = 128; off > 0; off >>= 1) {
        if (tid < off) { ps[tid] += ps[tid + off]; pq[tid] += pq[tid + off]; }
        __syncthreads();
    }
    if (tid == 0) {
        float mean = ps[0] * (1.f / 36864.f);
        float var  = pq[0] * (1.f / 36864.f) - mean * mean;
        float a = g1[f] * rsqrtf(var + EPS);
        ws[A1O + f] = a;
        ws[C1O + f] = b1[f] - mean * a;
    }
}

// K4: FC partials (BN1 already finalized). grid (256, 4)
__global__ void k_fc(const float* __restrict__ xbuf, const float* __restrict__ fc_w,
                     const float* __restrict__ ws, float* __restrict__ part) {
    __shared__ float a1s[100], c1s[100];
    __shared__ float xs[4][900];
    int tid = threadIdx.x;
    int sb = blockIdx.x, kc = blockIdx.y;
    if (tid < 100) { a1s[tid] = ws[A1O + tid]; c1s[tid] = ws[C1O + tid]; }
    __syncthreads();
    int b0s = sb * 4, k0 = kc * 900;
    for (int idx = tid; idx < 3600; idx += 256) {
        int s = idx / 900, k = idx - s * 900;
        int kg = k0 + k;
        int f = kg / 36;
        float v = xbuf[(long)(b0s + s) * 3600 + kg];
        v = a1s[f] * v + c1s[f];
        xs[s][k] = v > 0.f ? v : 0.f;
    }
    __syncthreads();
    if (tid < 200) {
        int j = tid % 100, sg = tid / 100;
        float acc0 = 0.f, acc1 = 0.f;
        const float4* wrow = (const float4*)(fc_w + (long)j * 3600 + k0);
        const float4* x0 = (const float4*)(&xs[sg][0]);
        const float4* x1 = (const float4*)(&xs[sg + 2][0]);
#pragma unroll 5
        for (int kk = 0; kk < 225; kk++) {
            float4 w4 = wrow[kk];
            float4 a4 = x0[kk], b4 = x1[kk];
            acc0 += w4.x * a4.x + w4.y * a4.y + w4.z * a4.z + w4.w * a4.w;
            acc1 += w4.x * b4.x + w4.y * b4.y + w4.z * b4.z + w4.w * b4.w;
        }
        part[((long)kc * 1024 + b0s + sg) * 100 + j]     = acc0;
        part[((long)kc * 1024 + b0s + sg + 2) * 100 + j] = acc1;
    }
}

// K5: combine FC partials + fc_b, BN2 stats + apply + ReLU -> xhat bf16 [1024][128]
__global__ void k_bn2x(const float* __restrict__ part, const float* __restrict__ fc_b,
                       const float* __restrict__ g2, const float* __restrict__ b2,
                       unsigned short* __restrict__ xhat) {
    int j = blockIdx.x, tid = threadIdx.x;
    if (j >= 100) {
        for (int t = 0; t < 4; t++) xhat[(long)(tid + t * 256) * 128 + j] = 0;
        return;
    }
    __shared__ float ps[256], pq[256];
    __shared__ float ab[2];
    float v[4];
    float s = 0.f, q = 0.f;
#pragma unroll
    for (int t = 0; t < 4; t++) {
        int b = tid + t * 256;
        float x = part[(long)b * 100 + j] + part[(long)(1024 + b) * 100 + j]
                + part[(long)(2048 + b) * 100 + j] + part[(long)(3072 + b) * 100 + j]
                + fc_b[j];
        v[t] = x; s += x; q += x * x;
    }
    ps[tid] = s; pq[tid] = q;
    __syncthreads();
    for (int off = 128; off > 0; off >>= 1) {
        if (tid < off) { ps[tid] += ps[tid + off]; pq[tid] += pq[tid + off]; }
        __syncthreads();
    }
    if (tid == 0) {
        float mean = ps[0] * (1.f / 1024.f);
        float var  = pq[0] * (1.f / 1024.f) - mean * mean;
        float a = g2[j] * rsqrtf(var + EPS);
        ab[0] = a; ab[1] = b2[j] - mean * a;
    }
    __syncthreads();
    float a = ab[0], c = ab[1];
#pragma unroll
    for (int t = 0; t < 4; t++) {
        float x = a * v[t] + c;
        x = x > 0.f ? x : 0.f;
        xhat[(long)(tid + t * 256) * 128 + j] = f2bf(x);
    }
}

// K6: logits = Xhat @ emb_e^T + bias, sigmoid.  M=1024 N=100000 K=128(pad)
// BARRIER-FREE: everything is wave-local. Wave w owns E rows (= out cols)
// n0+32w..n0+32w+31 and its own 8 KB LDS stripe; per chunk it transposes its
// 64x32 acc sub-tile in-stripe (XOR slot swizzle), reads rows back, NT-stores
// 128 B segments. No __syncthreads -> stores drain across chunk boundaries.
__global__ void __launch_bounds__(256, 4)
k_gemm(const unsigned short* __restrict__ xhat, const float* __restrict__ emb_e,
       const float* __restrict__ bias, float* __restrict__ out) {
    __shared__ __align__(16) unsigned short Es[128 * 128];  // 32 KB; 8KB stripe per wave
    char* EsB = (char*)Es;
    int tid = threadIdx.x;
    int n0 = blockIdx.x * 128;

    // ---- stage E tile (bf16, byte ^= (row&7)<<4): 2 threads per row (wave-local rows) ----
    {
        int r = tid >> 1, p = tid & 1;
        int g = n0 + r;
        unsigned int rowb = (unsigned)r * 256u;
        unsigned int sw = ((unsigned)r & 7u) << 4;
        ushort4 z; z.x = z.y = z.z = z.w = 0;
        if (g < NENT) {
            const float4* src = (const float4*)(emb_e + (long)g * 100);
            for (int i = p; i < 25; i += 2) {
                float4 v = src[i];
                ushort4 h;
                h.x = f2bf(v.x); h.y = f2bf(v.y); h.z = f2bf(v.z); h.w = f2bf(v.w);
                *(ushort4*)(EsB + ((rowb + 8u * i) ^ sw)) = h;
            }
        } else {
            for (int i = p; i < 25; i += 2) *(ushort4*)(EsB + ((rowb + 8u * i) ^ sw)) = z;
        }
        for (int zz = p; zz < 7; zz += 2) *(ushort4*)(EsB + ((rowb + 200u + 8u * zz) ^ sw)) = z;
    }

    int w = tid >> 6, l = tid & 63;
    int l15 = l & 15, l4 = l >> 4;

    // ---- hoist A (E) fragments to regs (reads only THIS wave's rows) ----
    bf16x8 Af[4][2];
#pragma unroll
    for (int fe = 0; fe < 2; fe++) {
        unsigned int r = (unsigned)(w * 32 + fe * 16 + l15);
        unsigned int base = r * 256u + (unsigned)(l4 * 16);
        unsigned int sw = (r & 7u) << 4;
#pragma unroll
        for (int ks = 0; ks < 4; ks++)
            Af[ks][fe] = *(const bf16x8*)(EsB + ((base + (unsigned)(ks * 64)) ^ sw));
    }

    // wave-private transpose stripe
    char* wbase = EsB + w * 8192;
    // write offsets: row = fx*16+l15 (row&7 == l15&7), slot = (fe*4+l4) ^ (l15&7)
    int l7 = l15 & 7;
    unsigned int woff[2][4];
#pragma unroll
    for (int fe = 0; fe < 2; fe++) {
        unsigned int slot = (unsigned)((fe * 4 + l4) ^ l7);
#pragma unroll
        for (int fx = 0; fx < 4; fx++)
            woff[fe][fx] = (unsigned)(fx * 16 + l15) * 128u + slot * 16u;
    }
    // readback: lane j=l&7 owns cols j*4..j*4+3; subrow k=l>>3; slot read = j^k (constant)
    int rj = l & 7, rk = l >> 3;
    unsigned int roff = (unsigned)rk * 128u + (unsigned)((rj ^ rk) & 7) * 16u;
    int colg = n0 + w * 32 + rj * 4;
    bool colv = colg < NENT;   // wave-uniform except none/all in last block
    f32x4 bb = colv ? *(const f32x4*)(bias + colg) : f32x4{0.f, 0.f, 0.f, 0.f};

    int xrow = l15 * 128 + l4 * 8;   // element offset into xhat

    // prefetch chunk 0, ks 0
    bf16x8 Bp[4];
#pragma unroll
    for (int fx = 0; fx < 4; fx++)
        Bp[fx] = *(const bf16x8*)(xhat + (long)(fx * 2048 + xrow));

    for (int chunk = 0; chunk < 16; ++chunk) {
        int m0 = chunk * 64;
        f32x4 acc[2][4];
#pragma unroll
        for (int fe = 0; fe < 2; fe++)
#pragma unroll
            for (int fx = 0; fx < 4; fx++) acc[fe][fx] = f32x4{0.f, 0.f, 0.f, 0.f};

#pragma unroll
        for (int fe = 0; fe < 2; fe++)
#pragma unroll
            for (int fx = 0; fx < 4; fx++)
                acc[fe][fx] = __builtin_amdgcn_mfma_f32_16x16x32_bf16(Af[0][fe], Bp[fx], acc[fe][fx], 0, 0, 0);

#pragma unroll
        for (int ks = 1; ks < 4; ++ks) {
            bf16x8 Bf[4];
#pragma unroll
            for (int fx = 0; fx < 4; fx++)
                Bf[fx] = *(const bf16x8*)(xhat + (long)(m0 * 128 + fx * 2048 + ks * 32 + xrow));
#pragma unroll
            for (int fe = 0; fe < 2; fe++)
#pragma unroll
                for (int fx = 0; fx < 4; fx++)
                    acc[fe][fx] = __builtin_amdgcn_mfma_f32_16x16x32_bf16(Af[ks][fe], Bf[fx], acc[fe][fx], 0, 0, 0);
        }

        // prefetch next chunk ks=0 (hides under epilogue)
        if (chunk < 15) {
            int m0n = (chunk + 1) * 64;
#pragma unroll
            for (int fx = 0; fx < 4; fx++)
                Bp[fx] = *(const bf16x8*)(xhat + (long)(m0n * 128 + fx * 2048 + xrow));
        }

        // ---- wave-private transpose epilogue (no barriers) ----
#pragma unroll
        for (int fe = 0; fe < 2; fe++)
#pragma unroll
            for (int fx = 0; fx < 4; fx++)
                *(f32x4*)(wbase + woff[fe][fx]) = acc[fe][fx];
#pragma unroll
        for (int pass = 0; pass < 8; pass++) {
            f32x4 v = *(f32x4*)(wbase + (unsigned)(pass * 1024) + roff);
            f32x4 o;
#pragma unroll
            for (int k = 0; k < 4; k++) {
                float x = v[k] + bb[k];
                float e = __builtin_amdgcn_exp2f(x * -1.44269504f);
                o[k] = __builtin_amdgcn_rcpf(1.0f + e);
            }
            if (colv)
                __builtin_nontemporal_store(o, (f32x4*)(out + (long)(m0 + pass * 8 + rk) * NENT + colg));
        }
    }
}

extern "C" void kernel_launch(void* const* d_in, const int* in_sizes, int n_in,
                              void* d_out, int out_size, void* d_ws, size_t ws_size,
                              hipStream_t stream) {
    const int*   e1      = (const int*)d_in[0];
    const int*   rel     = (const int*)d_in[1];
    const float* emb_e   = (const float*)d_in[2];
    const float* emb_rel = (const float*)d_in[3];
    const float* fc_w    = (const float*)d_in[4];
    const float* fc_b    = (const float*)d_in[5];
    const float* bias    = (const float*)d_in[6];
    const float* g0      = (const float*)d_in[7];
    const float* b0      = (const float*)d_in[8];
    const float* g1      = (const float*)d_in[9];
    const float* b1      = (const float*)d_in[10];
    const float* grel    = (const float*)d_in[11];
    const float* brel    = (const float*)d_in[12];
    const float* g2      = (const float*)d_in[13];
    const float* b2      = (const float*)d_in[14];
    float* ws  = (float*)d_ws;
    float* out = (float*)d_out;

    hipLaunchKernelGGL(k_stats, dim3(56), dim3(512), 0, stream, rel, emb_rel, grel, brel, e1, emb_e, ws);
    hipLaunchKernelGGL(k_conv, dim3(1024), dim3(256), 0, stream, e1, rel, emb_e, emb_rel, g0, b0,
                       ws, ws + XBUF_OFF, ws + PART_OFF);
    hipLaunchKernelGGL(k_bn1r, dim3(100), dim3(256), 0, stream, ws + PART_OFF, g1, b1, ws);
    hipLaunchKernelGGL(k_fc, dim3(256, 4), dim3(256), 0, stream, ws + XBUF_OFF, fc_w, ws, ws + PART_OFF);
    hipLaunchKernelGGL(k_bn2x, dim3(128), dim3(256), 0, stream, ws + PART_OFF, fc_b, g2, b2,
                       (unsigned short*)(ws + XHAT_OFF));
    hipLaunchKernelGGL(k_gemm, dim3(782), dim3(256), 0, stream,
                       (const unsigned short*)(ws + XHAT_OFF), emb_e, bias, out);
}

// Round 8
// 207.051 us; speedup vs baseline: 3.0095x; 1.2516x over previous
//
#include <hip/hip_runtime.h>
#include <cstdint>

#define NENT 100000
#define EPS 1e-5f

// ---- ws layout (float offsets) ----
constexpr long REL_A    = 0;        // 2500
constexpr long REL_B    = 2500;     // 2500
constexpr long EPART    = 5000;     // 32 (16 blocks x {sum, sumsq})
constexpr long A1O      = 5056;     // 100
constexpr long C1O      = 5156;     // 100
constexpr long PART_OFF = 5888;     // 4*1024*100 = 409600  (also hosts conv bn1-partials [1024][200] early)
constexpr long XBUF_OFF = 415488;   // 1024*3600  = 3686400
constexpr long XHAT_OFF = 4101888;  // 1024*128 bf16 = 65536 floats

typedef __attribute__((ext_vector_type(8))) __bf16 bf16x8;
typedef __attribute__((ext_vector_type(4))) float  f32x4;

#define BARLK() asm volatile("s_waitcnt lgkmcnt(0)\n\ts_barrier" ::: "memory")

__device__ __forceinline__ unsigned short f2bf(float f) {
    unsigned int u = __float_as_uint(f);
    unsigned int r = (u + 0x7FFFu + ((u >> 16) & 1u)) >> 16;
    return (unsigned short)r;
}

// K1 (512 thr): blocks 0..39  -> rel-BN stats via 500-bin histogram (emb_rel read ONCE, 8-wave row split)
//               blocks 40..55 -> e-BN0 partial sums (16 blocks x 64 gathered rows)
__global__ void k_stats(const int* __restrict__ rel, const float* __restrict__ emb_rel,
                        const float* __restrict__ grel, const float* __restrict__ brel,
                        const int* __restrict__ e1, const float* __restrict__ emb_e,
                        float* __restrict__ ws) {
    __shared__ float cntf[512];
    __shared__ float ps[512], pq[512];
    int tid = threadIdx.x, blk = blockIdx.x;
    if (blk < 40) {
        int* cnti = (int*)cntf;
        cnti[tid] = 0;
        __syncthreads();
        for (int i = tid; i < 1024; i += 512) atomicAdd(&cnti[rel[i]], 1);
        __syncthreads();
        cntf[tid] = (float)cnti[tid];
        __syncthreads();
        int f = blk * 64 + (tid & 63);
        int w = tid >> 6;           // 8 waves, rows strided by 8
        float s = 0.f, q = 0.f;
        const float* base = emb_rel + f;
#pragma unroll 4
        for (int r = w; r < 500; r += 8) {
            float c = cntf[r];      // wave-uniform broadcast
            if (c != 0.f) {
                float v = base[(long)r * 2500];
                s = fmaf(c, v, s);
                q = fmaf(c * v, v, q);
            }
        }
        ps[tid] = s; pq[tid] = q;
        __syncthreads();
        if (tid < 64) {
            float ss = 0.f, qq = 0.f;
#pragma unroll
            for (int k = 0; k < 8; k++) { ss += ps[tid + k * 64]; qq += pq[tid + k * 64]; }
            float mean = ss * (1.f / 1024.f);
            float var  = qq * (1.f / 1024.f) - mean * mean;
            float a = grel[f] * rsqrtf(var + EPS);
            ws[REL_A + f] = a;
            ws[REL_B + f] = brel[f] - mean * a;
        }
    } else if (blk < 56) {
        int* eidx = (int*)cntf;
        int bi = blk - 40;
        if (tid < 64) eidx[tid] = e1[bi * 64 + tid];
        __syncthreads();
        float s = 0.f, q = 0.f;
        for (int i = tid; i < 6400; i += 512) {
            int b = i / 100, d = i - b * 100;
            float v = emb_e[(long)eidx[b] * 100 + d];
            s += v; q += v * v;
        }
        ps[tid] = s; pq[tid] = q;
        __syncthreads();
        for (int off = 256; off > 0; off >>= 1) {
            if (tid < off) { ps[tid] += ps[tid + off]; pq[tid] += pq[tid + off]; }
            __syncthreads();
        }
        if (tid == 0) { ws[EPART + bi * 2] = ps[0]; ws[EPART + bi * 2 + 1] = pq[0]; }
    }
}

// K2: per-sample grouped conv 10x10 * (100 x 5x5) -> [B,100,6,6]; emits per-channel
//     (sum,sumsq) partials for BN1 into part region [b][200]
__global__ void k_conv(const int* __restrict__ e1, const int* __restrict__ rel,
                       const float* __restrict__ emb_e, const float* __restrict__ emb_rel,
                       const float* __restrict__ g0, const float* __restrict__ b0,
                       const float* __restrict__ ws, float* __restrict__ xout,
                       float* __restrict__ bn1part) {
    __shared__ float es[100];
    __shared__ float flt[2500];
    __shared__ float a0c0[2];
    __shared__ float prs[600], prq[600];
    int b = blockIdx.x, tid = threadIdx.x;
    if (tid == 0) {
        float s = 0.f, q = 0.f;
#pragma unroll
        for (int i = 0; i < 16; i++) { s += ws[EPART + 2 * i]; q += ws[EPART + 2 * i + 1]; }
        float mean = s * (1.f / 102400.f);
        float var  = q * (1.f / 102400.f) - mean * mean;
        float a = g0[0] * rsqrtf(var + EPS);
        a0c0[0] = a; a0c0[1] = b0[0] - mean * a;
    }
    __syncthreads();
    float a0 = a0c0[0], c0 = a0c0[1];
    long ebase = (long)e1[b] * 100;
    for (int i = tid; i < 100; i += 256) es[i] = a0 * emb_e[ebase + i] + c0;
    long rbase = (long)rel[b] * 2500;
    for (int i = tid; i < 2500; i += 256) flt[i] = ws[REL_A + i] * emb_rel[rbase + i] + ws[REL_B + i];
    __syncthreads();
    for (int u = tid; u < 600; u += 256) {
        int f = u / 6, oi = u - f * 6;
        float er[5][10];
#pragma unroll
        for (int p = 0; p < 5; p++)
#pragma unroll
            for (int c = 0; c < 10; c++) er[p][c] = es[(oi + p) * 10 + c];
        float fw[25];
#pragma unroll
        for (int k = 0; k < 25; k++) fw[k] = flt[f * 25 + k];
        float* dst = xout + (long)b * 3600 + f * 36 + oi * 6;
        float s6 = 0.f, q6 = 0.f;
#pragma unroll
        for (int oj = 0; oj < 6; oj++) {
            float acc = 0.f;
#pragma unroll
            for (int p = 0; p < 5; p++)
#pragma unroll
                for (int q = 0; q < 5; q++) acc += er[p][oj + q] * fw[p * 5 + q];
            dst[oj] = acc;
            s6 += acc; q6 = fmaf(acc, acc, q6);
        }
        prs[u] = s6; prq[u] = q6;
    }
    __syncthreads();
    if (tid < 100) {
        float s = 0.f, q = 0.f;
#pragma unroll
        for (int k = 0; k < 6; k++) { s += prs[tid * 6 + k]; q += prq[tid * 6 + k]; }
        bn1part[(long)b * 200 + tid]       = s;
        bn1part[(long)b * 200 + 100 + tid] = q;
    }
}

// K3: reduce BN1 partials over 1024 blocks -> a1s/c1s (tiny, L2-resident)
__global__ void k_bn1r(const float* __restrict__ bn1part, const float* __restrict__ g1,
                       const float* __restrict__ b1, float* __restrict__ ws) {
    __shared__ float ps[256], pq[256];
    int f = blockIdx.x, tid = threadIdx.x;
    float s = 0.f, q = 0.f;
    for (int b = tid; b < 1024; b += 256) {
        s += bn1part[(long)b * 200 + f];
        q += bn1part[(long)b * 200 + 100 + f];
    }
    ps[tid] = s; pq[tid] = q;
    __syncthreads();
    for (int off = 128; off > 0; off >>= 1) {
        if (tid < off) { ps[tid] += ps[tid + off]; pq[tid] += pq[tid + off]; }
        __syncthreads();
    }
    if (tid == 0) {
        float mean = ps[0] * (1.f / 36864.f);
        float var  = pq[0] * (1.f / 36864.f) - mean * mean;
        float a = g1[f] * rsqrtf(var + EPS);
        ws[A1O + f] = a;
        ws[C1O + f] = b1[f] - mean * a;
    }
}

// K4: FC partials (BN1 already finalized). grid (256, 4)
__global__ void k_fc(const float* __restrict__ xbuf, const float* __restrict__ fc_w,
                     const float* __restrict__ ws, float* __restrict__ part) {
    __shared__ float a1s[100], c1s[100];
    __shared__ float xs[4][900];
    int tid = threadIdx.x;
    int sb = blockIdx.x, kc = blockIdx.y;
    if (tid < 100) { a1s[tid] = ws[A1O + tid]; c1s[tid] = ws[C1O + tid]; }
    __syncthreads();
    int b0s = sb * 4, k0 = kc * 900;
    for (int idx = tid; idx < 3600; idx += 256) {
        int s = idx / 900, k = idx - s * 900;
        int kg = k0 + k;
        int f = kg / 36;
        float v = xbuf[(long)(b0s + s) * 3600 + kg];
        v = a1s[f] * v + c1s[f];
        xs[s][k] = v > 0.f ? v : 0.f;
    }
    __syncthreads();
    if (tid < 200) {
        int j = tid % 100, sg = tid / 100;
        float acc0 = 0.f, acc1 = 0.f;
        const float4* wrow = (const float4*)(fc_w + (long)j * 3600 + k0);
        const float4* x0 = (const float4*)(&xs[sg][0]);
        const float4* x1 = (const float4*)(&xs[sg + 2][0]);
#pragma unroll 5
        for (int kk = 0; kk < 225; kk++) {
            float4 w4 = wrow[kk];
            float4 a4 = x0[kk], b4 = x1[kk];
            acc0 += w4.x * a4.x + w4.y * a4.y + w4.z * a4.z + w4.w * a4.w;
            acc1 += w4.x * b4.x + w4.y * b4.y + w4.z * b4.z + w4.w * b4.w;
        }
        part[((long)kc * 1024 + b0s + sg) * 100 + j]     = acc0;
        part[((long)kc * 1024 + b0s + sg + 2) * 100 + j] = acc1;
    }
}

// K5: combine FC partials + fc_b, BN2 stats + apply + ReLU -> xhat bf16 [1024][128]
__global__ void k_bn2x(const float* __restrict__ part, const float* __restrict__ fc_b,
                       const float* __restrict__ g2, const float* __restrict__ b2,
                       unsigned short* __restrict__ xhat) {
    int j = blockIdx.x, tid = threadIdx.x;
    if (j >= 100) {
        for (int t = 0; t < 4; t++) xhat[(long)(tid + t * 256) * 128 + j] = 0;
        return;
    }
    __shared__ float ps[256], pq[256];
    __shared__ float ab[2];
    float v[4];
    float s = 0.f, q = 0.f;
#pragma unroll
    for (int t = 0; t < 4; t++) {
        int b = tid + t * 256;
        float x = part[(long)b * 100 + j] + part[(long)(1024 + b) * 100 + j]
                + part[(long)(2048 + b) * 100 + j] + part[(long)(3072 + b) * 100 + j]
                + fc_b[j];
        v[t] = x; s += x; q += x * x;
    }
    ps[tid] = s; pq[tid] = q;
    __syncthreads();
    for (int off = 128; off > 0; off >>= 1) {
        if (tid < off) { ps[tid] += ps[tid + off]; pq[tid] += pq[tid + off]; }
        __syncthreads();
    }
    if (tid == 0) {
        float mean = ps[0] * (1.f / 1024.f);
        float var  = pq[0] * (1.f / 1024.f) - mean * mean;
        float a = g2[j] * rsqrtf(var + EPS);
        ab[0] = a; ab[1] = b2[j] - mean * a;
    }
    __syncthreads();
    float a = ab[0], c = ab[1];
#pragma unroll
    for (int t = 0; t < 4; t++) {
        float x = a * v[t] + c;
        x = x > 0.f ? x : 0.f;
        xhat[(long)(tid + t * 256) * 128 + j] = f2bf(x);
    }
}

// K6: logits = Xhat @ emb_e^T + bias, sigmoid.  M=1024 N=100000 K=128(pad)
// N-tile 256: grid 391, 64 KB LDS E-tile (reused as float[64][256] transpose buf).
// Per chunk: 64 MFMA/wave -> block transpose -> each WAVE-instruction NT-stores a
// 1 KB contiguous row run. Barriers = lgkmcnt-only (stores drain across chunks).
__global__ void __launch_bounds__(256, 2)
k_gemm(const unsigned short* __restrict__ xhat, const float* __restrict__ emb_e,
       const float* __restrict__ bias, float* __restrict__ out) {
    __shared__ __align__(16) unsigned short Es[256 * 128];  // 64 KB
    char* EsB = (char*)Es;
    int tid = threadIdx.x;
    int n0 = blockIdx.x * 256;

    // ---- stage E tile (bf16, byte ^= (row&7)<<4): 1 thread per row ----
    {
        int r = tid;
        int g = n0 + r;
        unsigned int rowb = (unsigned)r * 256u;
        unsigned int sw = ((unsigned)r & 7u) << 4;
        ushort4 z; z.x = z.y = z.z = z.w = 0;
        if (g < NENT) {
            const float4* src = (const float4*)(emb_e + (long)g * 100);
#pragma unroll
            for (int i = 0; i < 25; i++) {
                float4 v = src[i];
                ushort4 h;
                h.x = f2bf(v.x); h.y = f2bf(v.y); h.z = f2bf(v.z); h.w = f2bf(v.w);
                *(ushort4*)(EsB + ((rowb + 8u * i) ^ sw)) = h;
            }
        } else {
#pragma unroll
            for (int i = 0; i < 25; i++) *(ushort4*)(EsB + ((rowb + 8u * i) ^ sw)) = z;
        }
#pragma unroll
        for (int zz = 0; zz < 7; zz++) *(ushort4*)(EsB + ((rowb + 200u + 8u * zz) ^ sw)) = z;
    }
    __syncthreads();

    int w = tid >> 6, l = tid & 63;
    int l15 = l & 15, l4 = l >> 4;

    // ---- hoist ALL A (E) fragments: wave w owns ents n0+w*64 .. +63 ----
    bf16x8 Af[4][4];   // [ks][fe]
#pragma unroll
    for (int fe = 0; fe < 4; fe++) {
        unsigned int r = (unsigned)(w * 64 + fe * 16 + l15);
        unsigned int base = r * 256u + (unsigned)(l4 * 16);
        unsigned int sw = (r & 7u) << 4;
#pragma unroll
        for (int ks = 0; ks < 4; ks++)
            Af[ks][fe] = *(const bf16x8*)(EsB + ((base + (unsigned)(ks * 64)) ^ sw));
    }
    BARLK();   // Es dead as bf16 tile; reuse as float[64 rows][256 cols]

    // per-lane output columns (store phase): lane l owns cols n0 + l*4 .. +3
    int colg = n0 + l * 4;
    bool colv = colg < NENT;               // NENT % 4 == 0 -> all-or-none per lane
    f32x4 bb = colv ? *(const f32x4*)(bias + colg) : f32x4{0.f, 0.f, 0.f, 0.f};

    int xrow = l15 * 128 + l4 * 8;   // element offset into xhat

    // prefetch chunk 0, ks 0
    bf16x8 Bp[4];
#pragma unroll
    for (int fx = 0; fx < 4; fx++)
        Bp[fx] = *(const bf16x8*)(xhat + (long)(fx * 2048 + xrow));

    for (int chunk = 0; chunk < 16; ++chunk) {
        int m0 = chunk * 64;
        f32x4 acc[4][4];   // [fe][fx]
#pragma unroll
        for (int fe = 0; fe < 4; fe++)
#pragma unroll
            for (int fx = 0; fx < 4; fx++) acc[fe][fx] = f32x4{0.f, 0.f, 0.f, 0.f};

#pragma unroll
        for (int fe = 0; fe < 4; fe++)
#pragma unroll
            for (int fx = 0; fx < 4; fx++)
                acc[fe][fx] = __builtin_amdgcn_mfma_f32_16x16x32_bf16(Af[0][fe], Bp[fx], acc[fe][fx], 0, 0, 0);

#pragma unroll
        for (int ks = 1; ks < 4; ++ks) {
            bf16x8 Bf[4];
#pragma unroll
            for (int fx = 0; fx < 4; fx++)
                Bf[fx] = *(const bf16x8*)(xhat + (long)(m0 * 128 + fx * 2048 + ks * 32 + xrow));
#pragma unroll
            for (int fe = 0; fe < 4; fe++)
#pragma unroll
                for (int fx = 0; fx < 4; fx++)
                    acc[fe][fx] = __builtin_amdgcn_mfma_f32_16x16x32_bf16(Af[ks][fe], Bf[fx], acc[fe][fx], 0, 0, 0);
        }

        // prefetch next chunk ks=0 (hides under epilogue)
        if (chunk < 15) {
            int m0n = (chunk + 1) * 64;
#pragma unroll
            for (int fx = 0; fx < 4; fx++)
                Bp[fx] = *(const bf16x8*)(xhat + (long)(m0n * 128 + fx * 2048 + xrow));
        }

        // ---- block-wide transpose: acc[fe][fx] -> float[row=fx*16+l15][slot^(row&7)] ----
#pragma unroll
        for (int fe = 0; fe < 4; fe++) {
            unsigned int s = (unsigned)(w * 16 + fe * 4 + l4);
#pragma unroll
            for (int fx = 0; fx < 4; fx++) {
                unsigned int row = (unsigned)(fx * 16 + l15);
                *(f32x4*)(EsB + row * 1024u + ((s ^ (row & 7u)) * 16u)) = acc[fe][fx];
            }
        }
        BARLK();

        // ---- store: wave w covers row pass*4+w; 64 lanes x 16B = 1 KB contiguous NT ----
#pragma unroll
        for (int pass = 0; pass < 16; pass++) {
            unsigned int row = (unsigned)(pass * 4 + w);
            f32x4 v = *(f32x4*)(EsB + row * 1024u + ((((unsigned)l) ^ (row & 7u)) * 16u));
            f32x4 o;
#pragma unroll
            for (int k = 0; k < 4; k++) {
                float x = v[k] + bb[k];
                float e = __builtin_amdgcn_exp2f(x * -1.44269504f);
                o[k] = __builtin_amdgcn_rcpf(1.0f + e);
            }
            if (colv)
                __builtin_nontemporal_store(o, (f32x4*)(out + (long)(m0 + row) * NENT + colg));
        }
        BARLK();
    }
}

extern "C" void kernel_launch(void* const* d_in, const int* in_sizes, int n_in,
                              void* d_out, int out_size, void* d_ws, size_t ws_size,
                              hipStream_t stream) {
    const int*   e1      = (const int*)d_in[0];
    const int*   rel     = (const int*)d_in[1];
    const float* emb_e   = (const float*)d_in[2];
    const float* emb_rel = (const float*)d_in[3];
    const float* fc_w    = (const float*)d_in[4];
    const float* fc_b    = (const float*)d_in[5];
    const float* bias    = (const float*)d_in[6];
    const float* g0      = (const float*)d_in[7];
    const float* b0      = (const float*)d_in[8];
    const float* g1      = (const float*)d_in[9];
    const float* b1      = (const float*)d_in[10];
    const float* grel    = (const float*)d_in[11];
    const float* brel    = (const float*)d_in[12];
    const float* g2      = (const float*)d_in[13];
    const float* b2      = (const float*)d_in[14];
    float* ws  = (float*)d_ws;
    float* out = (float*)d_out;

    hipLaunchKernelGGL(k_stats, dim3(56), dim3(512), 0, stream, rel, emb_rel, grel, brel, e1, emb_e, ws);
    hipLaunchKernelGGL(k_conv, dim3(1024), dim3(256), 0, stream, e1, rel, emb_e, emb_rel, g0, b0,
                       ws, ws + XBUF_OFF, ws + PART_OFF);
    hipLaunchKernelGGL(k_bn1r, dim3(100), dim3(256), 0, stream, ws + PART_OFF, g1, b1, ws);
    hipLaunchKernelGGL(k_fc, dim3(256, 4), dim3(256), 0, stream, ws + XBUF_OFF, fc_w, ws, ws + PART_OFF);
    hipLaunchKernelGGL(k_bn2x, dim3(128), dim3(256), 0, stream, ws + PART_OFF, fc_b, g2, b2,
                       (unsigned short*)(ws + XHAT_OFF));
    hipLaunchKernelGGL(k_gemm, dim3(391), dim3(256), 0, stream,
                       (const unsigned short*)(ws + XHAT_OFF), emb_e, bias, out);
}

// Round 9
// 201.772 us; speedup vs baseline: 3.0882x; 1.0262x over previous
//
#include <hip/hip_runtime.h>
#include <cstdint>

#define NENT 100000
#define EPS 1e-5f

// ---- ws layout (float offsets) ----
constexpr long REL_A    = 0;        // 2500
constexpr long REL_B    = 2500;     // 2500
constexpr long EPART    = 5000;     // 32 (16 blocks x {sum, sumsq})
constexpr long EAB      = 5040;     // 2 (a0, c0 finalized)
constexpr long A1O      = 5056;     // 100
constexpr long C1O      = 5156;     // 100
constexpr long PART_OFF = 5888;     // 4*1024*100 = 409600  (also hosts conv bn1-partials [1024][200] early)
constexpr long XBUF_OFF = 415488;   // 1024*3600  = 3686400  (hosts rel-stat partials [125][5000] BEFORE conv)
constexpr long XHAT_OFF = 4101888;  // 1024*128 bf16 = 65536 floats
constexpr long PSTAT    = XBUF_OFF; // 625000 floats, dead once k_stats2 completes

typedef __attribute__((ext_vector_type(8))) __bf16 bf16x8;
typedef __attribute__((ext_vector_type(4))) float  f32x4;

#define BARLK() asm volatile("s_waitcnt lgkmcnt(0)\n\ts_barrier" ::: "memory")

__device__ __forceinline__ unsigned short f2bf(float f) {
    unsigned int u = __float_as_uint(f);
    unsigned int r = (u + 0x7FFFu + ((u >> 16) & 1u)) >> 16;
    return (unsigned short)r;
}

// K1a: blocks 0..124  -> rel-stat partials: each block streams 4 relation rows COALESCED,
//                        weights by count histogram, accumulates in regs -> [125][5000]
//      blocks 125..140 -> e-BN0 partial sums (16 blocks x 64 gathered rows)
__global__ void k_stats1(const int* __restrict__ rel, const float* __restrict__ emb_rel,
                         const int* __restrict__ e1, const float* __restrict__ emb_e,
                         float* __restrict__ ws) {
    __shared__ float shmem[512];
    int tid = threadIdx.x, blk = blockIdx.x;
    if (blk < 125) {
        int* cnti = (int*)shmem;
        for (int i = tid; i < 512; i += 256) cnti[i] = 0;
        __syncthreads();
        for (int i = tid; i < 1024; i += 256) atomicAdd(&cnti[rel[i]], 1);
        __syncthreads();
        float s[10], q[10];
#pragma unroll
        for (int k = 0; k < 10; k++) { s[k] = 0.f; q[k] = 0.f; }
#pragma unroll
        for (int rr = 0; rr < 4; rr++) {
            int r = blk * 4 + rr;
            float c = (float)cnti[r];
            if (c != 0.f) {
                const float* row = emb_rel + (long)r * 2500;
#pragma unroll
                for (int k = 0; k < 10; k++) {
                    int idx = tid + k * 256;
                    if (idx < 2500) {
                        float v = row[idx];
                        s[k] = fmaf(c, v, s[k]);
                        q[k] = fmaf(c * v, v, q[k]);
                    }
                }
            }
        }
        float* ps = ws + PSTAT + (long)blk * 5000;
#pragma unroll
        for (int k = 0; k < 10; k++) {
            int idx = tid + k * 256;
            if (idx < 2500) { ps[idx] = s[k]; ps[2500 + idx] = q[k]; }
        }
    } else if (blk < 141) {
        float* ps = shmem;
        __shared__ float pq[256];
        __shared__ int eidx[64];
        int bi = blk - 125;
        if (tid < 64) eidx[tid] = e1[bi * 64 + tid];
        __syncthreads();
        float s = 0.f, q = 0.f;
        for (int i = tid; i < 6400; i += 256) {
            int b = i / 100, d = i - b * 100;
            float v = emb_e[(long)eidx[b] * 100 + d];
            s += v; q += v * v;
        }
        ps[tid] = s; pq[tid] = q;
        __syncthreads();
        for (int off = 128; off > 0; off >>= 1) {
            if (tid < off) { ps[tid] += ps[tid + off]; pq[tid] += pq[tid + off]; }
            __syncthreads();
        }
        if (tid == 0) { ws[EPART + bi * 2] = ps[0]; ws[EPART + bi * 2 + 1] = pq[0]; }
    }
}

// K1b (512 thr): blocks 0..39 -> reduce [125][5000] partials (L2-resident) -> REL_A/REL_B
//                block 40     -> finalize e-BN0 scalars -> ws[EAB]
__global__ void k_stats2(const float* __restrict__ grel, const float* __restrict__ brel,
                         const float* __restrict__ g0, const float* __restrict__ b0,
                         float* __restrict__ ws) {
    __shared__ float ps[512], pq[512];
    int tid = threadIdx.x, blk = blockIdx.x;
    if (blk < 40) {
        int f = blk * 64 + (tid & 63);
        int g = tid >> 6;   // 8 row-groups
        float s = 0.f, q = 0.f;
        for (int p = g; p < 125; p += 8) {
            s += ws[PSTAT + (long)p * 5000 + f];
            q += ws[PSTAT + (long)p * 5000 + 2500 + f];
        }
        ps[tid] = s; pq[tid] = q;
        __syncthreads();
        if (tid < 64) {
            float ss = 0.f, qq = 0.f;
#pragma unroll
            for (int k = 0; k < 8; k++) { ss += ps[tid + k * 64]; qq += pq[tid + k * 64]; }
            float mean = ss * (1.f / 1024.f);
            float var  = qq * (1.f / 1024.f) - mean * mean;
            float a = grel[f] * rsqrtf(var + EPS);
            ws[REL_A + f] = a;
            ws[REL_B + f] = brel[f] - mean * a;
        }
    } else if (tid == 0) {
        float s = 0.f, q = 0.f;
#pragma unroll
        for (int i = 0; i < 16; i++) { s += ws[EPART + 2 * i]; q += ws[EPART + 2 * i + 1]; }
        float mean = s * (1.f / 102400.f);
        float var  = q * (1.f / 102400.f) - mean * mean;
        float a = g0[0] * rsqrtf(var + EPS);
        ws[EAB]     = a;
        ws[EAB + 1] = b0[0] - mean * a;
    }
}

// K2: per-sample grouped conv 10x10 * (100 x 5x5) -> [B,100,6,6]; emits per-channel
//     (sum,sumsq) partials for BN1 into part region [b][200]
__global__ void k_conv(const int* __restrict__ e1, const int* __restrict__ rel,
                       const float* __restrict__ emb_e, const float* __restrict__ emb_rel,
                       const float* __restrict__ ws, float* __restrict__ xout,
                       float* __restrict__ bn1part) {
    __shared__ float es[100];
    __shared__ float flt[2500];
    __shared__ float prs[600], prq[600];
    int b = blockIdx.x, tid = threadIdx.x;
    float a0 = ws[EAB], c0 = ws[EAB + 1];
    long ebase = (long)e1[b] * 100;
    for (int i = tid; i < 100; i += 256) es[i] = a0 * emb_e[ebase + i] + c0;
    long rbase = (long)rel[b] * 2500;
    for (int i = tid; i < 2500; i += 256) flt[i] = ws[REL_A + i] * emb_rel[rbase + i] + ws[REL_B + i];
    __syncthreads();
    for (int u = tid; u < 600; u += 256) {
        int f = u / 6, oi = u - f * 6;
        float er[5][10];
#pragma unroll
        for (int p = 0; p < 5; p++)
#pragma unroll
            for (int c = 0; c < 10; c++) er[p][c] = es[(oi + p) * 10 + c];
        float fw[25];
#pragma unroll
        for (int k = 0; k < 25; k++) fw[k] = flt[f * 25 + k];
        float* dst = xout + (long)b * 3600 + f * 36 + oi * 6;
        float s6 = 0.f, q6 = 0.f;
#pragma unroll
        for (int oj = 0; oj < 6; oj++) {
            float acc = 0.f;
#pragma unroll
            for (int p = 0; p < 5; p++)
#pragma unroll
                for (int q = 0; q < 5; q++) acc += er[p][oj + q] * fw[p * 5 + q];
            dst[oj] = acc;
            s6 += acc; q6 = fmaf(acc, acc, q6);
        }
        prs[u] = s6; prq[u] = q6;
    }
    __syncthreads();
    if (tid < 100) {
        float s = 0.f, q = 0.f;
#pragma unroll
        for (int k = 0; k < 6; k++) { s += prs[tid * 6 + k]; q += prq[tid * 6 + k]; }
        bn1part[(long)b * 200 + tid]       = s;
        bn1part[(long)b * 200 + 100 + tid] = q;
    }
}

// K3: reduce BN1 partials over 1024 blocks -> a1s/c1s (tiny, L2-resident)
__global__ void k_bn1r(const float* __restrict__ bn1part, const float* __restrict__ g1,
                       const float* __restrict__ b1, float* __restrict__ ws) {
    __shared__ float ps[256], pq[256];
    int f = blockIdx.x, tid = threadIdx.x;
    float s = 0.f, q = 0.f;
    for (int b = tid; b < 1024; b += 256) {
        s += bn1part[(long)b * 200 + f];
        q += bn1part[(long)b * 200 + 100 + f];
    }
    ps[tid] = s; pq[tid] = q;
    __syncthreads();
    for (int off = 128; off > 0; off >>= 1) {
        if (tid < off) { ps[tid] += ps[tid + off]; pq[tid] += pq[tid + off]; }
        __syncthreads();
    }
    if (tid == 0) {
        float mean = ps[0] * (1.f / 36864.f);
        float var  = pq[0] * (1.f / 36864.f) - mean * mean;
        float a = g1[f] * rsqrtf(var + EPS);
        ws[A1O + f] = a;
        ws[C1O + f] = b1[f] - mean * a;
    }
}

// K4: FC partials (BN1 already finalized). grid (256, 4)
__global__ void k_fc(const float* __restrict__ xbuf, const float* __restrict__ fc_w,
                     const float* __restrict__ ws, float* __restrict__ part) {
    __shared__ float a1s[100], c1s[100];
    __shared__ float xs[4][900];
    int tid = threadIdx.x;
    int sb = blockIdx.x, kc = blockIdx.y;
    if (tid < 100) { a1s[tid] = ws[A1O + tid]; c1s[tid] = ws[C1O + tid]; }
    __syncthreads();
    int b0s = sb * 4, k0 = kc * 900;
    for (int idx = tid; idx < 3600; idx += 256) {
        int s = idx / 900, k = idx - s * 900;
        int kg = k0 + k;
        int f = kg / 36;
        float v = xbuf[(long)(b0s + s) * 3600 + kg];
        v = a1s[f] * v + c1s[f];
        xs[s][k] = v > 0.f ? v : 0.f;
    }
    __syncthreads();
    if (tid < 200) {
        int j = tid % 100, sg = tid / 100;
        float acc0 = 0.f, acc1 = 0.f;
        const float4* wrow = (const float4*)(fc_w + (long)j * 3600 + k0);
        const float4* x0 = (const float4*)(&xs[sg][0]);
        const float4* x1 = (const float4*)(&xs[sg + 2][0]);
#pragma unroll 5
        for (int kk = 0; kk < 225; kk++) {
            float4 w4 = wrow[kk];
            float4 a4 = x0[kk], b4 = x1[kk];
            acc0 += w4.x * a4.x + w4.y * a4.y + w4.z * a4.z + w4.w * a4.w;
            acc1 += w4.x * b4.x + w4.y * b4.y + w4.z * b4.z + w4.w * b4.w;
        }
        part[((long)kc * 1024 + b0s + sg) * 100 + j]     = acc0;
        part[((long)kc * 1024 + b0s + sg + 2) * 100 + j] = acc1;
    }
}

// K5: combine FC partials + fc_b, BN2 stats + apply + ReLU -> xhat bf16 [1024][128]
__global__ void k_bn2x(const float* __restrict__ part, const float* __restrict__ fc_b,
                       const float* __restrict__ g2, const float* __restrict__ b2,
                       unsigned short* __restrict__ xhat) {
    int j = blockIdx.x, tid = threadIdx.x;
    if (j >= 100) {
        for (int t = 0; t < 4; t++) xhat[(long)(tid + t * 256) * 128 + j] = 0;
        return;
    }
    __shared__ float ps[256], pq[256];
    __shared__ float ab[2];
    float v[4];
    float s = 0.f, q = 0.f;
#pragma unroll
    for (int t = 0; t < 4; t++) {
        int b = tid + t * 256;
        float x = part[(long)b * 100 + j] + part[(long)(1024 + b) * 100 + j]
                + part[(long)(2048 + b) * 100 + j] + part[(long)(3072 + b) * 100 + j]
                + fc_b[j];
        v[t] = x; s += x; q += x * x;
    }
    ps[tid] = s; pq[tid] = q;
    __syncthreads();
    for (int off = 128; off > 0; off >>= 1) {
        if (tid < off) { ps[tid] += ps[tid + off]; pq[tid] += pq[tid + off]; }
        __syncthreads();
    }
    if (tid == 0) {
        float mean = ps[0] * (1.f / 1024.f);
        float var  = pq[0] * (1.f / 1024.f) - mean * mean;
        float a = g2[j] * rsqrtf(var + EPS);
        ab[0] = a; ab[1] = b2[j] - mean * a;
    }
    __syncthreads();
    float a = ab[0], c = ab[1];
#pragma unroll
    for (int t = 0; t < 4; t++) {
        float x = a * v[t] + c;
        x = x > 0.f ? x : 0.f;
        xhat[(long)(tid + t * 256) * 128 + j] = f2bf(x);
    }
}

// K6: logits = Xhat @ emb_e^T + bias, sigmoid.  M=1024 N=100000 K=128(pad)
// N-tile 256: grid 391, 64 KB LDS E-tile (reused as float[64][256] transpose buf).
// Per chunk: 64 MFMA/wave -> block transpose -> each WAVE-instruction NT-stores a
// 1 KB contiguous row run. Barriers = lgkmcnt-only (stores drain across chunks).
__global__ void __launch_bounds__(256, 2)
k_gemm(const unsigned short* __restrict__ xhat, const float* __restrict__ emb_e,
       const float* __restrict__ bias, float* __restrict__ out) {
    __shared__ __align__(16) unsigned short Es[256 * 128];  // 64 KB
    char* EsB = (char*)Es;
    int tid = threadIdx.x;
    int n0 = blockIdx.x * 256;

    // ---- stage E tile (bf16, byte ^= (row&7)<<4): 1 thread per row ----
    {
        int r = tid;
        int g = n0 + r;
        unsigned int rowb = (unsigned)r * 256u;
        unsigned int sw = ((unsigned)r & 7u) << 4;
        ushort4 z; z.x = z.y = z.z = z.w = 0;
        if (g < NENT) {
            const float4* src = (const float4*)(emb_e + (long)g * 100);
#pragma unroll
            for (int i = 0; i < 25; i++) {
                float4 v = src[i];
                ushort4 h;
                h.x = f2bf(v.x); h.y = f2bf(v.y); h.z = f2bf(v.z); h.w = f2bf(v.w);
                *(ushort4*)(EsB + ((rowb + 8u * i) ^ sw)) = h;
            }
        } else {
#pragma unroll
            for (int i = 0; i < 25; i++) *(ushort4*)(EsB + ((rowb + 8u * i) ^ sw)) = z;
        }
#pragma unroll
        for (int zz = 0; zz < 7; zz++) *(ushort4*)(EsB + ((rowb + 200u + 8u * zz) ^ sw)) = z;
    }
    __syncthreads();

    int w = tid >> 6, l = tid & 63;
    int l15 = l & 15, l4 = l >> 4;

    // ---- hoist ALL A (E) fragments: wave w owns ents n0+w*64 .. +63 ----
    bf16x8 Af[4][4];   // [ks][fe]
#pragma unroll
    for (int fe = 0; fe < 4; fe++) {
        unsigned int r = (unsigned)(w * 64 + fe * 16 + l15);
        unsigned int base = r * 256u + (unsigned)(l4 * 16);
        unsigned int sw = (r & 7u) << 4;
#pragma unroll
        for (int ks = 0; ks < 4; ks++)
            Af[ks][fe] = *(const bf16x8*)(EsB + ((base + (unsigned)(ks * 64)) ^ sw));
    }
    BARLK();   // Es dead as bf16 tile; reuse as float[64 rows][256 cols]

    // per-lane output columns (store phase): lane l owns cols n0 + l*4 .. +3
    int colg = n0 + l * 4;
    bool colv = colg < NENT;               // NENT % 4 == 0 -> all-or-none per lane
    f32x4 bb = colv ? *(const f32x4*)(bias + colg) : f32x4{0.f, 0.f, 0.f, 0.f};

    int xrow = l15 * 128 + l4 * 8;   // element offset into xhat

    // prefetch chunk 0, ks 0
    bf16x8 Bp[4];
#pragma unroll
    for (int fx = 0; fx < 4; fx++)
        Bp[fx] = *(const bf16x8*)(xhat + (long)(fx * 2048 + xrow));

    for (int chunk = 0; chunk < 16; ++chunk) {
        int m0 = chunk * 64;
        f32x4 acc[4][4];   // [fe][fx]
#pragma unroll
        for (int fe = 0; fe < 4; fe++)
#pragma unroll
            for (int fx = 0; fx < 4; fx++) acc[fe][fx] = f32x4{0.f, 0.f, 0.f, 0.f};

#pragma unroll
        for (int fe = 0; fe < 4; fe++)
#pragma unroll
            for (int fx = 0; fx < 4; fx++)
                acc[fe][fx] = __builtin_amdgcn_mfma_f32_16x16x32_bf16(Af[0][fe], Bp[fx], acc[fe][fx], 0, 0, 0);

#pragma unroll
        for (int ks = 1; ks < 4; ++ks) {
            bf16x8 Bf[4];
#pragma unroll
            for (int fx = 0; fx < 4; fx++)
                Bf[fx] = *(const bf16x8*)(xhat + (long)(m0 * 128 + fx * 2048 + ks * 32 + xrow));
#pragma unroll
            for (int fe = 0; fe < 4; fe++)
#pragma unroll
                for (int fx = 0; fx < 4; fx++)
                    acc[fe][fx] = __builtin_amdgcn_mfma_f32_16x16x32_bf16(Af[ks][fe], Bf[fx], acc[fe][fx], 0, 0, 0);
        }

        // prefetch next chunk ks=0 (hides under epilogue)
        if (chunk < 15) {
            int m0n = (chunk + 1) * 64;
#pragma unroll
            for (int fx = 0; fx < 4; fx++)
                Bp[fx] = *(const bf16x8*)(xhat + (long)(m0n * 128 + fx * 2048 + xrow));
        }

        // ---- block-wide transpose: acc[fe][fx] -> float[row=fx*16+l15][slot^(row&7)] ----
#pragma unroll
        for (int fe = 0; fe < 4; fe++) {
            unsigned int s = (unsigned)(w * 16 + fe * 4 + l4);
#pragma unroll
            for (int fx = 0; fx < 4; fx++) {
                unsigned int row = (unsigned)(fx * 16 + l15);
                *(f32x4*)(EsB + row * 1024u + ((s ^ (row & 7u)) * 16u)) = acc[fe][fx];
            }
        }
        BARLK();

        // ---- store: wave w covers row pass*4+w; 64 lanes x 16B = 1 KB contiguous NT ----
#pragma unroll
        for (int pass = 0; pass < 16; pass++) {
            unsigned int row = (unsigned)(pass * 4 + w);
            f32x4 v = *(f32x4*)(EsB + row * 1024u + ((((unsigned)l) ^ (row & 7u)) * 16u));
            f32x4 o;
#pragma unroll
            for (int k = 0; k < 4; k++) {
                float x = v[k] + bb[k];
                float e = __builtin_amdgcn_exp2f(x * -1.44269504f);
                o[k] = __builtin_amdgcn_rcpf(1.0f + e);
            }
            if (colv)
                __builtin_nontemporal_store(o, (f32x4*)(out + (long)(m0 + row) * NENT + colg));
        }
        BARLK();
    }
}

extern "C" void kernel_launch(void* const* d_in, const int* in_sizes, int n_in,
                              void* d_out, int out_size, void* d_ws, size_t ws_size,
                              hipStream_t stream) {
    const int*   e1      = (const int*)d_in[0];
    const int*   rel     = (const int*)d_in[1];
    const float* emb_e   = (const float*)d_in[2];
    const float* emb_rel = (const float*)d_in[3];
    const float* fc_w    = (const float*)d_in[4];
    const float* fc_b    = (const float*)d_in[5];
    const float* bias    = (const float*)d_in[6];
    const float* g0      = (const float*)d_in[7];
    const float* b0      = (const float*)d_in[8];
    const float* g1      = (const float*)d_in[9];
    const float* b1      = (const float*)d_in[10];
    const float* grel    = (const float*)d_in[11];
    const float* brel    = (const float*)d_in[12];
    const float* g2      = (const float*)d_in[13];
    const float* b2      = (const float*)d_in[14];
    float* ws  = (float*)d_ws;
    float* out = (float*)d_out;

    hipLaunchKernelGGL(k_stats1, dim3(141), dim3(256), 0, stream, rel, emb_rel, e1, emb_e, ws);
    hipLaunchKernelGGL(k_stats2, dim3(41), dim3(512), 0, stream, grel, brel, g0, b0, ws);
    hipLaunchKernelGGL(k_conv, dim3(1024), dim3(256), 0, stream, e1, rel, emb_e, emb_rel,
                       ws, ws + XBUF_OFF, ws + PART_OFF);
    hipLaunchKernelGGL(k_bn1r, dim3(100), dim3(256), 0, stream, ws + PART_OFF, g1, b1, ws);
    hipLaunchKernelGGL(k_fc, dim3(256, 4), dim3(256), 0, stream, ws + XBUF_OFF, fc_w, ws, ws + PART_OFF);
    hipLaunchKernelGGL(k_bn2x, dim3(128), dim3(256), 0, stream, ws + PART_OFF, fc_b, g2, b2,
                       (unsigned short*)(ws + XHAT_OFF));
    hipLaunchKernelGGL(k_gemm, dim3(391), dim3(256), 0, stream,
                       (const unsigned short*)(ws + XHAT_OFF), emb_e, bias, out);
}

// Round 10
// 162.902 us; speedup vs baseline: 3.8251x; 1.2386x over previous
//
#include <hip/hip_runtime.h>
#include <cstdint>

#define NENT 100000
#define EPS 1e-5f

// ---- ws layout (float offsets) ----
constexpr long REL_A    = 0;        // 2500
constexpr long REL_B    = 2500;     // 2500
constexpr long EPART    = 5000;     // 32 (16 blocks x {sum, sumsq})
constexpr long EAB      = 5040;     // 2 (a0, c0 finalized)
constexpr long A1O      = 5056;     // 100
constexpr long C1O      = 5156;     // 100
constexpr long PART_OFF = 5888;     // 409600: bn1part [200][1024] early, then part [4][100][1024]
constexpr long XBUF_OFF = 415488;   // 1024*3600  = 3686400  (hosts rel-stat partials [125][5000] BEFORE conv)
constexpr long XHAT_OFF = 4101888;  // 1024*128 bf16 = 65536 floats
constexpr long PSTAT    = XBUF_OFF; // 625000 floats, dead once k_stats2 completes

typedef __attribute__((ext_vector_type(8))) __bf16 bf16x8;
typedef __attribute__((ext_vector_type(4))) float  f32x4;

#define BARLK() asm volatile("s_waitcnt lgkmcnt(0)\n\ts_barrier" ::: "memory")

__device__ __forceinline__ unsigned short f2bf(float f) {
    unsigned int u = __float_as_uint(f);
    unsigned int r = (u + 0x7FFFu + ((u >> 16) & 1u)) >> 16;
    return (unsigned short)r;
}

// K1a: blocks 0..124  -> rel-stat partials (4 rows/block, coalesced) -> [125][5000]
//      blocks 125..140 -> e-BN0 partial sums
__global__ void k_stats1(const int* __restrict__ rel, const float* __restrict__ emb_rel,
                         const int* __restrict__ e1, const float* __restrict__ emb_e,
                         float* __restrict__ ws) {
    __shared__ float shmem[512];
    int tid = threadIdx.x, blk = blockIdx.x;
    if (blk < 125) {
        int* cnti = (int*)shmem;
        for (int i = tid; i < 512; i += 256) cnti[i] = 0;
        __syncthreads();
        for (int i = tid; i < 1024; i += 256) atomicAdd(&cnti[rel[i]], 1);
        __syncthreads();
        float s[10], q[10];
#pragma unroll
        for (int k = 0; k < 10; k++) { s[k] = 0.f; q[k] = 0.f; }
#pragma unroll
        for (int rr = 0; rr < 4; rr++) {
            int r = blk * 4 + rr;
            float c = (float)cnti[r];
            if (c != 0.f) {
                const float* row = emb_rel + (long)r * 2500;
#pragma unroll
                for (int k = 0; k < 10; k++) {
                    int idx = tid + k * 256;
                    if (idx < 2500) {
                        float v = row[idx];
                        s[k] = fmaf(c, v, s[k]);
                        q[k] = fmaf(c * v, v, q[k]);
                    }
                }
            }
        }
        float* ps = ws + PSTAT + (long)blk * 5000;
#pragma unroll
        for (int k = 0; k < 10; k++) {
            int idx = tid + k * 256;
            if (idx < 2500) { ps[idx] = s[k]; ps[2500 + idx] = q[k]; }
        }
    } else if (blk < 141) {
        float* ps = shmem;
        __shared__ float pq[256];
        __shared__ int eidx[64];
        int bi = blk - 125;
        if (tid < 64) eidx[tid] = e1[bi * 64 + tid];
        __syncthreads();
        float s = 0.f, q = 0.f;
        for (int i = tid; i < 6400; i += 256) {
            int b = i / 100, d = i - b * 100;
            float v = emb_e[(long)eidx[b] * 100 + d];
            s += v; q += v * v;
        }
        ps[tid] = s; pq[tid] = q;
        __syncthreads();
        for (int off = 128; off > 0; off >>= 1) {
            if (tid < off) { ps[tid] += ps[tid + off]; pq[tid] += pq[tid + off]; }
            __syncthreads();
        }
        if (tid == 0) { ws[EPART + bi * 2] = ps[0]; ws[EPART + bi * 2 + 1] = pq[0]; }
    }
}

// K1b (512 thr): blocks 0..39 -> reduce partials -> REL_A/REL_B; block 40 -> EAB
__global__ void k_stats2(const float* __restrict__ grel, const float* __restrict__ brel,
                         const float* __restrict__ g0, const float* __restrict__ b0,
                         float* __restrict__ ws) {
    __shared__ float ps[512], pq[512];
    int tid = threadIdx.x, blk = blockIdx.x;
    if (blk < 40) {
        int f = blk * 64 + (tid & 63);
        int g = tid >> 6;   // 8 row-groups
        float s = 0.f, q = 0.f;
        for (int p = g; p < 125; p += 8) {
            s += ws[PSTAT + (long)p * 5000 + f];
            q += ws[PSTAT + (long)p * 5000 + 2500 + f];
        }
        ps[tid] = s; pq[tid] = q;
        __syncthreads();
        if (tid < 64) {
            float ss = 0.f, qq = 0.f;
#pragma unroll
            for (int k = 0; k < 8; k++) { ss += ps[tid + k * 64]; qq += pq[tid + k * 64]; }
            float mean = ss * (1.f / 1024.f);
            float var  = qq * (1.f / 1024.f) - mean * mean;
            float a = grel[f] * rsqrtf(var + EPS);
            ws[REL_A + f] = a;
            ws[REL_B + f] = brel[f] - mean * a;
        }
    } else if (tid == 0) {
        float s = 0.f, q = 0.f;
#pragma unroll
        for (int i = 0; i < 16; i++) { s += ws[EPART + 2 * i]; q += ws[EPART + 2 * i + 1]; }
        float mean = s * (1.f / 102400.f);
        float var  = q * (1.f / 102400.f) - mean * mean;
        float a = g0[0] * rsqrtf(var + EPS);
        ws[EAB]     = a;
        ws[EAB + 1] = b0[0] - mean * a;
    }
}

// K2: per-sample grouped conv; emits BN1 partials TRANSPOSED: bn1part[f][b] / [100+f][b]
__global__ void k_conv(const int* __restrict__ e1, const int* __restrict__ rel,
                       const float* __restrict__ emb_e, const float* __restrict__ emb_rel,
                       const float* __restrict__ ws, float* __restrict__ xout,
                       float* __restrict__ bn1part) {
    __shared__ float es[100];
    __shared__ float flt[2500];
    __shared__ float prs[600], prq[600];
    int b = blockIdx.x, tid = threadIdx.x;
    float a0 = ws[EAB], c0 = ws[EAB + 1];
    long ebase = (long)e1[b] * 100;
    for (int i = tid; i < 100; i += 256) es[i] = a0 * emb_e[ebase + i] + c0;
    long rbase = (long)rel[b] * 2500;
    for (int i = tid; i < 2500; i += 256) flt[i] = ws[REL_A + i] * emb_rel[rbase + i] + ws[REL_B + i];
    __syncthreads();
    for (int u = tid; u < 600; u += 256) {
        int f = u / 6, oi = u - f * 6;
        float er[5][10];
#pragma unroll
        for (int p = 0; p < 5; p++)
#pragma unroll
            for (int c = 0; c < 10; c++) er[p][c] = es[(oi + p) * 10 + c];
        float fw[25];
#pragma unroll
        for (int k = 0; k < 25; k++) fw[k] = flt[f * 25 + k];
        float* dst = xout + (long)b * 3600 + f * 36 + oi * 6;
        float s6 = 0.f, q6 = 0.f;
#pragma unroll
        for (int oj = 0; oj < 6; oj++) {
            float acc = 0.f;
#pragma unroll
            for (int p = 0; p < 5; p++)
#pragma unroll
                for (int q = 0; q < 5; q++) acc += er[p][oj + q] * fw[p * 5 + q];
            dst[oj] = acc;
            s6 += acc; q6 = fmaf(acc, acc, q6);
        }
        prs[u] = s6; prq[u] = q6;
    }
    __syncthreads();
    if (tid < 100) {
        float s = 0.f, q = 0.f;
#pragma unroll
        for (int k = 0; k < 6; k++) { s += prs[tid * 6 + k]; q += prq[tid * 6 + k]; }
        bn1part[(long)tid * 1024 + b]         = s;
        bn1part[(long)(100 + tid) * 1024 + b] = q;
    }
}

// K3: reduce BN1 partials (COALESCED rows) -> a1s/c1s
__global__ void k_bn1r(const float* __restrict__ bn1part, const float* __restrict__ g1,
                       const float* __restrict__ b1, float* __restrict__ ws) {
    __shared__ float ps[256], pq[256];
    int f = blockIdx.x, tid = threadIdx.x;
    float s = 0.f, q = 0.f;
    for (int b = tid; b < 1024; b += 256) {
        s += bn1part[(long)f * 1024 + b];
        q += bn1part[(long)(100 + f) * 1024 + b];
    }
    ps[tid] = s; pq[tid] = q;
    __syncthreads();
    for (int off = 128; off > 0; off >>= 1) {
        if (tid < off) { ps[tid] += ps[tid + off]; pq[tid] += pq[tid + off]; }
        __syncthreads();
    }
    if (tid == 0) {
        float mean = ps[0] * (1.f / 36864.f);
        float var  = pq[0] * (1.f / 36864.f) - mean * mean;
        float a = g1[f] * rsqrtf(var + EPS);
        ws[A1O + f] = a;
        ws[C1O + f] = b1[f] - mean * a;
    }
}

// K4: FC partials, COALESCED fc_w reads. grid (128, 4): 8 samples x 900-k chunk.
// Wave handles 4 outputs j at once (16-lane k-split each); shfl_xor tree reduce.
// part layout TRANSPOSED: part[(kc*100+j)*1024 + b]
__global__ void k_fc(const float* __restrict__ xbuf, const float* __restrict__ fc_w,
                     const float* __restrict__ ws, float* __restrict__ part) {
    __shared__ float a1s[100], c1s[100];
    __shared__ float xs[8][900];
    int tid = threadIdx.x;
    int sb = blockIdx.x, kc = blockIdx.y;
    if (tid < 100) { a1s[tid] = ws[A1O + tid]; c1s[tid] = ws[C1O + tid]; }
    __syncthreads();
    int b0s = sb * 8, k0 = kc * 900;
    for (int idx = tid; idx < 7200; idx += 256) {
        int s = idx / 900, k = idx - s * 900;
        int kg = k0 + k;
        int f = kg / 36;
        float v = xbuf[(long)(b0s + s) * 3600 + kg];
        v = a1s[f] * v + c1s[f];
        xs[s][k] = v > 0.f ? v : 0.f;
    }
    __syncthreads();
    int w = tid >> 6, l = tid & 63;
    int g = l >> 4, ks16 = l & 15;      // j-sub within group / k-lane
    for (int t = 0; t < 7; t++) {
        int grp = w + 4 * t;            // wave-uniform
        if (grp >= 25) break;
        int j = grp * 4 + g;
        const float* wrow = fc_w + (long)j * 3600 + k0;
        float acc[8];
#pragma unroll
        for (int s = 0; s < 8; s++) acc[s] = 0.f;
#pragma unroll
        for (int i = 0; i < 15; i++) {
            int kk = ks16 + i * 16;     // float4 index, 225 total
            if (kk < 225) {
                float4 w4 = *(const float4*)(wrow + kk * 4);
#pragma unroll
                for (int s = 0; s < 8; s++) {
                    float4 x4 = *(const float4*)(&xs[s][kk * 4]);
                    acc[s] += w4.x * x4.x + w4.y * x4.y + w4.z * x4.z + w4.w * x4.w;
                }
            }
        }
#pragma unroll
        for (int s = 0; s < 8; s++) {
            float v = acc[s];
            v += __shfl_xor(v, 1);
            v += __shfl_xor(v, 2);
            v += __shfl_xor(v, 4);
            v += __shfl_xor(v, 8);
            acc[s] = v;
        }
#pragma unroll
        for (int s = 0; s < 8; s++) {
            if (ks16 == s)
                part[((long)kc * 100 + j) * 1024 + b0s + s] = acc[s];
        }
    }
}

// K5: combine FC partials + fc_b, BN2 stats + apply + ReLU -> xhat bf16 [1024][128]
// part reads now COALESCED (lanes along b).
__global__ void k_bn2x(const float* __restrict__ part, const float* __restrict__ fc_b,
                       const float* __restrict__ g2, const float* __restrict__ b2,
                       unsigned short* __restrict__ xhat) {
    int j = blockIdx.x, tid = threadIdx.x;
    if (j >= 100) {
        for (int t = 0; t < 4; t++) xhat[(long)(tid + t * 256) * 128 + j] = 0;
        return;
    }
    __shared__ float ps[256], pq[256];
    __shared__ float ab[2];
    float v[4];
    float s = 0.f, q = 0.f;
#pragma unroll
    for (int t = 0; t < 4; t++) {
        int b = tid + t * 256;
        float x = part[(long)j * 1024 + b] + part[(long)(100 + j) * 1024 + b]
                + part[(long)(200 + j) * 1024 + b] + part[(long)(300 + j) * 1024 + b]
                + fc_b[j];
        v[t] = x; s += x; q += x * x;
    }
    ps[tid] = s; pq[tid] = q;
    __syncthreads();
    for (int off = 128; off > 0; off >>= 1) {
        if (tid < off) { ps[tid] += ps[tid + off]; pq[tid] += pq[tid + off]; }
        __syncthreads();
    }
    if (tid == 0) {
        float mean = ps[0] * (1.f / 1024.f);
        float var  = pq[0] * (1.f / 1024.f) - mean * mean;
        float a = g2[j] * rsqrtf(var + EPS);
        ab[0] = a; ab[1] = b2[j] - mean * a;
    }
    __syncthreads();
    float a = ab[0], c = ab[1];
#pragma unroll
    for (int t = 0; t < 4; t++) {
        float x = a * v[t] + c;
        x = x > 0.f ? x : 0.f;
        xhat[(long)(tid + t * 256) * 128 + j] = f2bf(x);
    }
}

// K6: logits GEMM (unchanged from round 8/9): N-tile 256, 1 KB contiguous NT row stores.
__global__ void __launch_bounds__(256, 2)
k_gemm(const unsigned short* __restrict__ xhat, const float* __restrict__ emb_e,
       const float* __restrict__ bias, float* __restrict__ out) {
    __shared__ __align__(16) unsigned short Es[256 * 128];  // 64 KB
    char* EsB = (char*)Es;
    int tid = threadIdx.x;
    int n0 = blockIdx.x * 256;

    {
        int r = tid;
        int g = n0 + r;
        unsigned int rowb = (unsigned)r * 256u;
        unsigned int sw = ((unsigned)r & 7u) << 4;
        ushort4 z; z.x = z.y = z.z = z.w = 0;
        if (g < NENT) {
            const float4* src = (const float4*)(emb_e + (long)g * 100);
#pragma unroll
            for (int i = 0; i < 25; i++) {
                float4 v = src[i];
                ushort4 h;
                h.x = f2bf(v.x); h.y = f2bf(v.y); h.z = f2bf(v.z); h.w = f2bf(v.w);
                *(ushort4*)(EsB + ((rowb + 8u * i) ^ sw)) = h;
            }
        } else {
#pragma unroll
            for (int i = 0; i < 25; i++) *(ushort4*)(EsB + ((rowb + 8u * i) ^ sw)) = z;
        }
#pragma unroll
        for (int zz = 0; zz < 7; zz++) *(ushort4*)(EsB + ((rowb + 200u + 8u * zz) ^ sw)) = z;
    }
    __syncthreads();

    int w = tid >> 6, l = tid & 63;
    int l15 = l & 15, l4 = l >> 4;

    bf16x8 Af[4][4];   // [ks][fe]
#pragma unroll
    for (int fe = 0; fe < 4; fe++) {
        unsigned int r = (unsigned)(w * 64 + fe * 16 + l15);
        unsigned int base = r * 256u + (unsigned)(l4 * 16);
        unsigned int sw = (r & 7u) << 4;
#pragma unroll
        for (int ks = 0; ks < 4; ks++)
            Af[ks][fe] = *(const bf16x8*)(EsB + ((base + (unsigned)(ks * 64)) ^ sw));
    }
    BARLK();   // Es dead as bf16 tile; reuse as float[64][256]

    int colg = n0 + l * 4;
    bool colv = colg < NENT;
    f32x4 bb = colv ? *(const f32x4*)(bias + colg) : f32x4{0.f, 0.f, 0.f, 0.f};

    int xrow = l15 * 128 + l4 * 8;

    bf16x8 Bp[4];
#pragma unroll
    for (int fx = 0; fx < 4; fx++)
        Bp[fx] = *(const bf16x8*)(xhat + (long)(fx * 2048 + xrow));

    for (int chunk = 0; chunk < 16; ++chunk) {
        int m0 = chunk * 64;
        f32x4 acc[4][4];
#pragma unroll
        for (int fe = 0; fe < 4; fe++)
#pragma unroll
            for (int fx = 0; fx < 4; fx++) acc[fe][fx] = f32x4{0.f, 0.f, 0.f, 0.f};

#pragma unroll
        for (int fe = 0; fe < 4; fe++)
#pragma unroll
            for (int fx = 0; fx < 4; fx++)
                acc[fe][fx] = __builtin_amdgcn_mfma_f32_16x16x32_bf16(Af[0][fe], Bp[fx], acc[fe][fx], 0, 0, 0);

#pragma unroll
        for (int ks = 1; ks < 4; ++ks) {
            bf16x8 Bf[4];
#pragma unroll
            for (int fx = 0; fx < 4; fx++)
                Bf[fx] = *(const bf16x8*)(xhat + (long)(m0 * 128 + fx * 2048 + ks * 32 + xrow));
#pragma unroll
            for (int fe = 0; fe < 4; fe++)
#pragma unroll
                for (int fx = 0; fx < 4; fx++)
                    acc[fe][fx] = __builtin_amdgcn_mfma_f32_16x16x32_bf16(Af[ks][fe], Bf[fx], acc[fe][fx], 0, 0, 0);
        }

        if (chunk < 15) {
            int m0n = (chunk + 1) * 64;
#pragma unroll
            for (int fx = 0; fx < 4; fx++)
                Bp[fx] = *(const bf16x8*)(xhat + (long)(m0n * 128 + fx * 2048 + xrow));
        }

#pragma unroll
        for (int fe = 0; fe < 4; fe++) {
            unsigned int s = (unsigned)(w * 16 + fe * 4 + l4);
#pragma unroll
            for (int fx = 0; fx < 4; fx++) {
                unsigned int row = (unsigned)(fx * 16 + l15);
                *(f32x4*)(EsB + row * 1024u + ((s ^ (row & 7u)) * 16u)) = acc[fe][fx];
            }
        }
        BARLK();

#pragma unroll
        for (int pass = 0; pass < 16; pass++) {
            unsigned int row = (unsigned)(pass * 4 + w);
            f32x4 v = *(f32x4*)(EsB + row * 1024u + ((((unsigned)l) ^ (row & 7u)) * 16u));
            f32x4 o;
#pragma unroll
            for (int k = 0; k < 4; k++) {
                float x = v[k] + bb[k];
                float e = __builtin_amdgcn_exp2f(x * -1.44269504f);
                o[k] = __builtin_amdgcn_rcpf(1.0f + e);
            }
            if (colv)
                __builtin_nontemporal_store(o, (f32x4*)(out + (long)(m0 + row) * NENT + colg));
        }
        BARLK();
    }
}

extern "C" void kernel_launch(void* const* d_in, const int* in_sizes, int n_in,
                              void* d_out, int out_size, void* d_ws, size_t ws_size,
                              hipStream_t stream) {
    const int*   e1      = (const int*)d_in[0];
    const int*   rel     = (const int*)d_in[1];
    const float* emb_e   = (const float*)d_in[2];
    const float* emb_rel = (const float*)d_in[3];
    const float* fc_w    = (const float*)d_in[4];
    const float* fc_b    = (const float*)d_in[5];
    const float* bias    = (const float*)d_in[6];
    const float* g0      = (const float*)d_in[7];
    const float* b0      = (const float*)d_in[8];
    const float* g1      = (const float*)d_in[9];
    const float* b1      = (const float*)d_in[10];
    const float* grel    = (const float*)d_in[11];
    const float* brel    = (const float*)d_in[12];
    const float* g2      = (const float*)d_in[13];
    const float* b2      = (const float*)d_in[14];
    float* ws  = (float*)d_ws;
    float* out = (float*)d_out;

    hipLaunchKernelGGL(k_stats1, dim3(141), dim3(256), 0, stream, rel, emb_rel, e1, emb_e, ws);
    hipLaunchKernelGGL(k_stats2, dim3(41), dim3(512), 0, stream, grel, brel, g0, b0, ws);
    hipLaunchKernelGGL(k_conv, dim3(1024), dim3(256), 0, stream, e1, rel, emb_e, emb_rel,
                       ws, ws + XBUF_OFF, ws + PART_OFF);
    hipLaunchKernelGGL(k_bn1r, dim3(100), dim3(256), 0, stream, ws + PART_OFF, g1, b1, ws);
    hipLaunchKernelGGL(k_fc, dim3(128, 4), dim3(256), 0, stream, ws + XBUF_OFF, fc_w, ws, ws + PART_OFF);
    hipLaunchKernelGGL(k_bn2x, dim3(128), dim3(256), 0, stream, ws + PART_OFF, fc_b, g2, b2,
                       (unsigned short*)(ws + XHAT_OFF));
    hipLaunchKernelGGL(k_gemm, dim3(391), dim3(256), 0, stream,
                       (const unsigned short*)(ws + XHAT_OFF), emb_e, bias, out);
}